// Round 10
// baseline (625.313 us; speedup 1.0000x reference)
//
#include <hip/hip_runtime.h>
#include <hip/hip_bf16.h>

#define N_NODES 30000
#define N_EDGES 480000
#define NFEAT 92
#define EFEAT 50
#define D1 64
#define ZD 178
#define NL 3
#define NG 256
#define BN_EPS 1e-5f
#define NTILES (N_EDGES / 16)     // 30000 tiles
#define EDGE_TPW 2                // R10: 2 tiles per wave, fully unrolled (ILP)
#define EDGE_WBLK 3750            // 30000 / (4 waves * 2 tiles)
#define EDGE_GRID 3752            // 8 XCDs x 469, guard vbid < 3750

#define LIN0_BLOCKS 512
#define CNT_BLOCKS 1875    // E / 256
#define WPREP_BLOCKS 96    // NL*16*64*8 / 256
#define SCAN_BLOCKS ((N_NODES + 255) / 256)  // 118
#define BUILD_BLOCKS 1875  // E / 256
#define NPM_BLOCKS 1875    // MFMA nodeproj: N_NODES/16 tiles, 1 per block

typedef __attribute__((ext_vector_type(8))) short bf16x8;
typedef __attribute__((ext_vector_type(8))) unsigned short u16x8;
typedef __attribute__((ext_vector_type(4))) unsigned short u16x4;
typedef __attribute__((ext_vector_type(4))) float f32x4;

static __device__ __forceinline__ unsigned short f2bf(float v) {
  __hip_bfloat16 b = __float2bfloat16(v);
  return *(unsigned short*)&b;
}
static __device__ __forceinline__ float bfu(unsigned short u) {
  union { unsigned int i; float f; } c;
  c.i = ((unsigned int)u) << 16;
  return c.f;
}

// ---------------- R8-proven MFMA nodeproj GEMM stage ----------------
static __device__ __forceinline__ void npm_gemm(
    int i0, const float* __restrict__ wfp, const float* __restrict__ wsm,
    unsigned short* __restrict__ projd_pk, unsigned short* __restrict__ projs_pk,
    const float (*hl)[68]) {
  const int lane = threadIdx.x & 63;
  const int w = threadIdx.x >> 6;  // 0..3: combo (Wf-dst, Wf-src, Ws-dst, Ws-src)
  const float* W = (w < 2) ? wfp : wsm;
  const int roff = (w & 1) * 64;
  unsigned short* pk = (w & 1) ? projs_pk : projd_pk;
  const int slot = (w < 2) ? 0 : 4;
  const int col = lane & 15;
  const int quad = lane >> 4;

  bf16x8 Bf[4][2];
#pragma unroll
  for (int ft = 0; ft < 4; ++ft)
#pragma unroll
    for (int kh = 0; kh < 2; ++kh) {
      bf16x8 bv;
#pragma unroll
      for (int j = 0; j < 8; ++j) {
        const float v = W[(size_t)(roff + kh * 32 + quad * 8 + j) * D1 + ft * 16 + col];
        ((unsigned short*)&bv)[j] = f2bf(v);
      }
      Bf[ft][kh] = bv;
    }

  bf16x8 A0, A1;
  {
    const float4* hr0 = (const float4*)&hl[col][quad * 8];
    const float4* hr1 = (const float4*)&hl[col][32 + quad * 8];
    const float4 a0 = hr0[0], a1 = hr0[1];
    const float4 b0 = hr1[0], b1 = hr1[1];
    ((unsigned short*)&A0)[0] = f2bf(a0.x); ((unsigned short*)&A0)[1] = f2bf(a0.y);
    ((unsigned short*)&A0)[2] = f2bf(a0.z); ((unsigned short*)&A0)[3] = f2bf(a0.w);
    ((unsigned short*)&A0)[4] = f2bf(a1.x); ((unsigned short*)&A0)[5] = f2bf(a1.y);
    ((unsigned short*)&A0)[6] = f2bf(a1.z); ((unsigned short*)&A0)[7] = f2bf(a1.w);
    ((unsigned short*)&A1)[0] = f2bf(b0.x); ((unsigned short*)&A1)[1] = f2bf(b0.y);
    ((unsigned short*)&A1)[2] = f2bf(b0.z); ((unsigned short*)&A1)[3] = f2bf(b0.w);
    ((unsigned short*)&A1)[4] = f2bf(b1.x); ((unsigned short*)&A1)[5] = f2bf(b1.y);
    ((unsigned short*)&A1)[6] = f2bf(b1.z); ((unsigned short*)&A1)[7] = f2bf(b1.w);
  }

#pragma unroll
  for (int ft = 0; ft < 4; ++ft) {
    f32x4 c = {0.0f, 0.0f, 0.0f, 0.0f};
    c = __builtin_amdgcn_mfma_f32_16x16x32_bf16(A0, Bf[ft][0], c, 0, 0, 0);
    c = __builtin_amdgcn_mfma_f32_16x16x32_bf16(A1, Bf[ft][1], c, 0, 0, 0);
    const int boff = (ft * 4 + (col >> 2)) * 8 + (col & 3) + slot;
#pragma unroll
    for (int r = 0; r < 4; ++r)
      pk[(size_t)(i0 + quad * 4 + r) * 128 + boff] = f2bf(c[r]);
  }
}

// ---------------- init: lin0 + dst counts + B fragments (block-range split) --
extern "C" __global__ void __launch_bounds__(256)
k_init(const float* __restrict__ x, const float* __restrict__ w,
       const float* __restrict__ b, float* __restrict__ h,
       const int* __restrict__ ei, int* __restrict__ cnt,
       const float* __restrict__ conv_wf, const float* __restrict__ conv_ws,
       unsigned short* __restrict__ Bp) {
  const int blk = blockIdx.x;
  if (blk < LIN0_BLOCKS) {
    const int lane = threadIdx.x & 63;
    const int wave = (blk * 256 + threadIdx.x) >> 6;
    const int nw = (LIN0_BLOCKS * 256) >> 6;
    float wreg[NFEAT];
#pragma unroll
    for (int k = 0; k < NFEAT; ++k) wreg[k] = w[k * D1 + lane];
    const float bj = b[lane];
    for (int i = wave; i < N_NODES; i += nw) {
      const float2* xr = (const float2*)(x + (size_t)i * NFEAT);
      float acc = bj;
#pragma unroll
      for (int k = 0; k < NFEAT / 2; ++k) {
        const float2 v = xr[k];
        acc = fmaf(v.x, wreg[2 * k], acc);
        acc = fmaf(v.y, wreg[2 * k + 1], acc);
      }
      h[(size_t)i * D1 + lane] = fmaxf(acc, 0.0f);
    }
  } else if (blk < LIN0_BLOCKS + CNT_BLOCKS) {
    const int e = (blk - LIN0_BLOCKS) * 256 + threadIdx.x;
    if (e < N_EDGES) atomicAdd(&cnt[ei[N_EDGES + e]], 1);
  } else {
    const int idx = (blk - LIN0_BLOCKS - CNT_BLOCKS) * 256 + threadIdx.x;
    const int j = idx & 7;
    const int lane = (idx >> 3) & 63;
    const int frag = (idx >> 9) & 15;  // (m*2+t)*4+n
    const int l = idx >> 13;
    const int n = frag & 3;
    const int t = (frag >> 2) & 1;
    const int m = frag >> 3;
    const int k = t * 32 + (lane >> 4) * 8 + j;
    const int feat = (lane & 15) * 4 + n;
    float v = 0.0f;
    if (k < EFEAT) {
      const float* W = (m == 0) ? conv_wf : conv_ws;
      v = W[(size_t)l * ZD * D1 + (size_t)(128 + k) * D1 + feat];
    }
    Bp[idx] = f2bf(v);
  }
}

// ---------------- scan phase 1: per-block partial sums ----------------
extern "C" __global__ void __launch_bounds__(256)
k_scan1(const int* __restrict__ cnt, int* __restrict__ lpre, int* __restrict__ ptot) {
  const int t = threadIdx.x;
  const int idx = blockIdx.x * 256 + t;
  const int v = (idx < N_NODES) ? cnt[idx] : 0;
  __shared__ int bs[256];
  bs[t] = v;
  __syncthreads();
  for (int off = 1; off < 256; off <<= 1) {
    int u = (t >= off) ? bs[t - off] : 0;
    __syncthreads();
    bs[t] += u;
    __syncthreads();
  }
  if (idx < N_NODES) lpre[idx] = bs[t] - v;
  if (t == 255) ptot[blockIdx.x] = bs[255];
}

// scan phase 2+3: redundant block-offset scan + wptr/invc/grp
extern "C" __global__ void __launch_bounds__(256)
k_scan23(const int* __restrict__ cnt, const int* __restrict__ lpre,
         const int* __restrict__ ptot, const int* __restrict__ batch,
         int* __restrict__ wptr, float* __restrict__ invc,
         int* __restrict__ grp) {
  __shared__ int bs[128];
  const int t = threadIdx.x;
  if (t < 128) bs[t] = (t < SCAN_BLOCKS) ? ptot[t] : 0;
  __syncthreads();
  for (int off = 1; off < 128; off <<= 1) {
    int u = 0;
    if (t < 128 && t >= off) u = bs[t - off];
    __syncthreads();
    if (t < 128 && t >= off) bs[t] += u;
    __syncthreads();
  }
  const int idx = blockIdx.x * 256 + t;
  if (idx >= N_NODES) return;
  const int bid = idx >> 8;
  const int boff = (bid == 0) ? 0 : bs[bid - 1];
  wptr[idx] = boff + lpre[idx];
  invc[idx] = 1.0f / fmaxf((float)cnt[idx], 1.0f);
  const int bt = batch[idx];
  if (idx == 0)
    for (int g = 0; g <= bt; ++g) grp[g] = 0;
  else {
    const int pb = batch[idx - 1];
    for (int g = pb + 1; g <= bt; ++g) grp[g] = idx;
  }
  if (idx == N_NODES - 1)
    for (int g = bt + 1; g <= NG; ++g) grp[g] = N_NODES;
}

// ---------------- build: CSR scatter + bf16 pack + MFMA nodeproj0 -----------
extern "C" __global__ void __launch_bounds__(256)
k_build(const int* __restrict__ ei, int* __restrict__ wptr,
        int2* __restrict__ ds2, const float* __restrict__ ea,
        unsigned short* __restrict__ eapb,
        const float* __restrict__ h0, const float* __restrict__ wfl,
        const float* __restrict__ wsl, unsigned short* __restrict__ projd_pk,
        unsigned short* __restrict__ projs_pk, float* __restrict__ aggrA) {
  __shared__ __align__(16) float hl[16][68];  // union: lpos (1KB) / h tile (4.25KB)
  if (blockIdx.x >= BUILD_BLOCKS) {
    const int i0 = (blockIdx.x - BUILD_BLOCKS) * 16;
    const int tid = threadIdx.x;
    {
      const int k = tid & 63;
#pragma unroll
      for (int jj = 0; jj < 4; ++jj) {
        const int row = (tid >> 6) + jj * 4;
        const int ii = i0 + row;
        const float hv = h0[(size_t)ii * D1 + k];
        aggrA[(size_t)ii * D1 + k] = 0.0f;
        hl[row][k] = hv;
      }
    }
    __syncthreads();
    npm_gemm(i0, wfl, wsl, projd_pk, projs_pk, hl);
    return;
  }
  int* lpos = (int*)hl;
  const int e0 = blockIdx.x * 256;
  {
    const int e = e0 + threadIdx.x;
    const int d = ei[N_EDGES + e];
    const int pos = atomicAdd(&wptr[d], 1);
    ds2[pos] = make_int2(d, ei[e]);  // one 8B scatter (half the sectors)
    lpos[threadIdx.x] = pos;
  }
  __syncthreads();
  const int l16 = threadIdx.x & 15;
  const int sub = threadIdx.x >> 4;  // 0..15
#pragma unroll
  for (int r = 0; r < 16; ++r) {
    const int eb = r * 16 + sub;
    const size_t ge = e0 + eb;
    const int pos = lpos[eb];
    unsigned short o0 = 0, o1 = 0, o2 = 0, o3 = 0;
    if (l16 < 12) {
      const float4 v = *(const float4*)(ea + ge * EFEAT + l16 * 4);
      o0 = f2bf(v.x); o1 = f2bf(v.y); o2 = f2bf(v.z); o3 = f2bf(v.w);
    } else if (l16 == 12) {
      const float2 v = *(const float2*)(ea + ge * EFEAT + 48);
      o0 = f2bf(v.x); o1 = f2bf(v.y);
    }
    u16x4 st;
    st[0] = o0; st[1] = o1; st[2] = o2; st[3] = o3;
    *(u16x4*)(eapb + ((size_t)pos << 6) + l16 * 4) = st;
  }
}

// ---------------- R8: MFMA node projection (layers 1,2) ----------------
extern "C" __global__ void __launch_bounds__(256)
k_npm(const float* __restrict__ hin, float* __restrict__ hout,
      const float* __restrict__ wfp, const float* __restrict__ wsm,
      unsigned short* __restrict__ projd_pk, unsigned short* __restrict__ projs_pk,
      const float* __restrict__ aggr, float* __restrict__ aggr_z,
      const float* __restrict__ invc,
      const float* __restrict__ musum, const float* __restrict__ sqsum,
      const float* __restrict__ gamma, const float* __restrict__ beta) {
  __shared__ float hl[16][68];  // +4 pad
  const int tid = threadIdx.x;
  const int i0 = blockIdx.x * 16;

  {
    const int k = tid & 63;
    const float mu = musum[k] * (1.0f / N_NODES);
    const float var = sqsum[k] * (1.0f / N_NODES) - mu * mu;
    const float r = gamma[k] * rsqrtf(var + BN_EPS);
    const float sh = beta[k] - mu * r;
#pragma unroll
    for (int jj = 0; jj < 4; ++jj) {
      const int row = (tid >> 6) + jj * 4;
      const int ii = i0 + row;
      float hv = hin[(size_t)ii * D1 + k];
      const float av = aggr[(size_t)ii * D1 + k] * invc[ii];
      hv = fmaxf(hv + fmaf(av, r, sh), 0.0f);
      hout[(size_t)ii * D1 + k] = hv;
      aggr_z[(size_t)ii * D1 + k] = 0.0f;
      hl[row][k] = hv;
    }
  }
  __syncthreads();
  npm_gemm(i0, wfp, wsm, projd_pk, projs_pk, hl);
}

// ---------------- MFMA edge kernel: 4 waves/block, 2 tiles/wave (R10) -------
// Both tiles fully unrolled: tile B's gathers issue under tile A's MFMA +
// epilogue (in-wave latency hiding); Bf/bias loads amortize 2x. 15000 waves
// keep wave-level parallelism (R4's regression used unroll 1 = no ILP).
extern "C" __global__ void __launch_bounds__(256)
k_edgemm(const unsigned short* __restrict__ projd_pk,
         const unsigned short* __restrict__ projs_pk,
         const unsigned short* __restrict__ eapb,
         const int2* __restrict__ ds2,
         const unsigned short* __restrict__ Bp,
         const float* __restrict__ bfp, const float* __restrict__ bsp,
         float* __restrict__ aggr, float* __restrict__ musum,
         float* __restrict__ sqsum) {
  const int lane = threadIdx.x & 63;
  const int wv = threadIdx.x >> 6;
  const int col = lane & 15;
  const int quad = lane >> 4;
  __shared__ float mlds[4][16][68];

  const int vbid = (blockIdx.x & 7) * 469 + (blockIdx.x >> 3);
  if (blockIdx.x == 0 && wv == 0) {  // zero stats accumulators for k_stats
    musum[lane] = 0.0f;
    sqsum[lane] = 0.0f;
  }
  if (vbid >= EDGE_WBLK) return;

  const int t0 = (vbid * 4 + wv) * EDGE_TPW;
  const int base[2] = {t0 * 16, t0 * 16 + 16};

  // tile-invariant loads (amortize over both tiles)
  bf16x8 Bf[2][2][4];
#pragma unroll
  for (int m = 0; m < 2; ++m)
#pragma unroll
    for (int tt = 0; tt < 2; ++tt)
#pragma unroll
      for (int n = 0; n < 4; ++n)
        Bf[m][tt][n] = *(const bf16x8*)(Bp + ((((m * 2 + tt) * 4 + n) * 64 + lane) * 8));
  const f32x4 bf4 = *(const f32x4*)(bfp + col * 4);
  const f32x4 bs4 = *(const f32x4*)(bsp + col * 4);

  // both tiles' front: idx + A-frags + gathered C init + MFMA (unrolled)
  int dr[2][4], sr[2][4];
  bf16x8 Af0[2], Af1[2];
  f32x4 aF[2][4], aS[2][4];
#pragma unroll
  for (int u = 0; u < 2; ++u) {
    const int4 p01 = *(const int4*)(ds2 + base[u] + quad * 4);
    const int4 p23 = *(const int4*)(ds2 + base[u] + quad * 4 + 2);
    dr[u][0] = p01.x; dr[u][1] = p01.z; dr[u][2] = p23.x; dr[u][3] = p23.z;
    sr[u][0] = p01.y; sr[u][1] = p01.w; sr[u][2] = p23.y; sr[u][3] = p23.w;
    Af0[u] = *(const bf16x8*)(eapb + ((size_t)(base[u] + col) << 6) + quad * 8);
    Af1[u] = *(const bf16x8*)(eapb + ((size_t)(base[u] + col) << 6) + 32 + quad * 8);
  }
#pragma unroll
  for (int u = 0; u < 2; ++u) {
#pragma unroll
    for (int r = 0; r < 4; ++r) {
      const u16x8 pd = *(const u16x8*)(projd_pk + (size_t)dr[u][r] * 128 + col * 8);
      const u16x8 ss = *(const u16x8*)(projs_pk + (size_t)sr[u][r] * 128 + col * 8);
#pragma unroll
      for (int n = 0; n < 4; ++n) {
        aF[u][n][r] = bfu(pd[n]) + bfu(ss[n]) + bf4[n];
        aS[u][n][r] = bfu(pd[n + 4]) + bfu(ss[n + 4]) + bs4[n];
      }
    }
#pragma unroll
    for (int n = 0; n < 4; ++n) {
      aF[u][n] = __builtin_amdgcn_mfma_f32_16x16x32_bf16(Af0[u], Bf[0][0][n], aF[u][n], 0, 0, 0);
      aF[u][n] = __builtin_amdgcn_mfma_f32_16x16x32_bf16(Af1[u], Bf[0][1][n], aF[u][n], 0, 0, 0);
      aS[u][n] = __builtin_amdgcn_mfma_f32_16x16x32_bf16(Af0[u], Bf[1][0][n], aS[u][n], 0, 0, 0);
      aS[u][n] = __builtin_amdgcn_mfma_f32_16x16x32_bf16(Af1[u], Bf[1][1][n], aS[u][n], 0, 0, 0);
    }
  }

  // epilogue + segmented reduce, per tile (mlds[wv] reused; wave-local sync)
#pragma unroll
  for (int u = 0; u < 2; ++u) {
#pragma unroll
    for (int r = 0; r < 4; ++r) {
      f32x4 mv;
#pragma unroll
      for (int n = 0; n < 4; ++n) {
        const float af = aF[u][n][r];
        const float as = aS[u][n][r];
        const float sg = __builtin_amdgcn_rcpf(1.0f + __expf(-af));
        const float sp = fmaxf(as, 0.0f) + __logf(1.0f + __expf(-fabsf(as)));
        mv[n] = sg * sp;
      }
      *(f32x4*)&mlds[wv][quad * 4 + r][col * 4] = mv;
    }
    __builtin_amdgcn_wave_barrier();
    float sum = 0.0f;
    int dcur = ds2[base[u]].x;
#pragma unroll
    for (int p = 0; p < 16; ++p) {
      sum += mlds[wv][p][lane];
      const int dnxt = (p < 15) ? ds2[base[u] + p + 1].x : -1;
      if (dnxt != dcur) {
        atomicAdd(&aggr[(size_t)dcur * D1 + lane], sum);
        sum = 0.0f;
        dcur = dnxt;
      }
    }
    __builtin_amdgcn_wave_barrier();  // reads done before next tile overwrites
  }
}

// ---------------- BN stats over aggr*invc ----------------
extern "C" __global__ void __launch_bounds__(256)
k_stats(const float* __restrict__ aggr, const float* __restrict__ invc,
        float* __restrict__ musum, float* __restrict__ sqsum) {
  const int j = threadIdx.x & 63;
  const int rid = (blockIdx.x * blockDim.x + threadIdx.x) >> 6;
  const int rstr = (gridDim.x * blockDim.x) >> 6;
  float s = 0.0f, sq = 0.0f;
  for (int i = rid; i < N_NODES; i += rstr) {
    const float v = aggr[(size_t)i * D1 + j] * invc[i];
    s += v;
    sq = fmaf(v, v, sq);
  }
  __shared__ float ls[256], lq[256];
  ls[threadIdx.x] = s;
  lq[threadIdx.x] = sq;
  __syncthreads();
  if (threadIdx.x < 64) {
    s = ls[j] + ls[64 + j] + ls[128 + j] + ls[192 + j];
    sq = lq[j] + lq[64 + j] + lq[128 + j] + lq[192 + j];
    atomicAdd(&musum[j], s);
    atomicAdd(&sqsum[j], sq);
  }
}

// ---------------- fused pool (final BN update) + MLP chain ------------------
extern "C" __global__ void __launch_bounds__(256)
k_poolmlp(const float* __restrict__ h, const float* __restrict__ aggr,
          const float* __restrict__ invc,
          const float* __restrict__ musum, const float* __restrict__ sqsum,
          const float* __restrict__ gamma, const float* __restrict__ beta,
          const int* __restrict__ grp,
          const float* __restrict__ lin1_w, const float* __restrict__ lin1_b,
          const float* __restrict__ fc_w, const float* __restrict__ fc_b,
          const float* __restrict__ lin2_w, const float* __restrict__ lin2_b,
          float* __restrict__ out) {
  const int g = blockIdx.x;
  const int lane = threadIdx.x & 63;
  const int wv = threadIdx.x >> 6;
  const float mu = musum[lane] * (1.0f / N_NODES);
  const float var = sqsum[lane] * (1.0f / N_NODES) - mu * mu;
  const float r = gamma[lane] * rsqrtf(var + BN_EPS);
  const float sh = beta[lane] - mu * r;
  const int s = grp[g], e = grp[g + 1];
  float acc = 0.0f;
  for (int i = s + wv; i < e; i += 4) {
    const float hv = h[(size_t)i * D1 + lane];
    const float av = aggr[(size_t)i * D1 + lane] * invc[i];
    acc += fmaxf(hv + fmaf(av, r, sh), 0.0f);
  }
  __shared__ float red[4][64];
  __shared__ float vin[64];
  red[wv][lane] = acc;
  __syncthreads();
  const int j = threadIdx.x;
  float v = 0.0f;
  if (j < 64) {
    const float inv = 1.0f / fmaxf((float)(e - s), 1.0f);
    v = (red[0][j] + red[1][j] + red[2][j] + red[3][j]) * inv;
  }
  for (int layer = 0; layer < 3; ++layer) {
    if (j < 64) vin[j] = v;
    __syncthreads();
    if (j < 64) {
      const float* W;
      const float* B;
      if (layer == 0) {
        W = lin1_w;
        B = lin1_b;
      } else {
        W = fc_w + (size_t)(layer - 1) * D1 * D1;
        B = fc_b + (size_t)(layer - 1) * D1;
      }
      float a2 = B[j];
#pragma unroll 16
      for (int k = 0; k < D1; ++k) a2 = fmaf(vin[k], W[k * D1 + j], a2);
      v = fmaxf(a2, 0.0f);
    }
    __syncthreads();
  }
  if (j < 64) {
    float p = v * lin2_w[j];
#pragma unroll
    for (int off = 32; off > 0; off >>= 1) p += __shfl_down(p, off);
    if (j == 0) out[g] = p + lin2_b[0];
  }
}

extern "C" void kernel_launch(void* const* d_in, const int* in_sizes, int n_in,
                              void* d_out, int out_size, void* d_ws, size_t ws_size,
                              hipStream_t stream) {
  const float* x        = (const float*)d_in[0];
  const float* ea       = (const float*)d_in[1];
  const float* lin0_w   = (const float*)d_in[2];
  const float* lin0_b   = (const float*)d_in[3];
  const float* conv_wf  = (const float*)d_in[4];
  const float* conv_bf  = (const float*)d_in[5];
  const float* conv_ws  = (const float*)d_in[6];
  const float* conv_bs  = (const float*)d_in[7];
  const float* bn_gamma = (const float*)d_in[8];
  const float* bn_beta  = (const float*)d_in[9];
  const float* lin1_w   = (const float*)d_in[10];
  const float* lin1_b   = (const float*)d_in[11];
  const float* fc_w     = (const float*)d_in[12];
  const float* fc_b     = (const float*)d_in[13];
  const float* lin2_w   = (const float*)d_in[14];
  const float* lin2_b   = (const float*)d_in[15];
  const int*   ei       = (const int*)d_in[16];
  const int*   batch    = (const int*)d_in[17];

  uintptr_t p = (uintptr_t)d_ws;
  auto alloc = [&](size_t bytes) {
    p = (p + 255) & ~(size_t)255;
    void* r = (void*)p;
    p += bytes;
    return r;
  };
  float* h0     = (float*)alloc((size_t)N_NODES * 64 * 4);
  float* h1     = (float*)alloc((size_t)N_NODES * 64 * 4);
  unsigned short* projd_pk = (unsigned short*)alloc((size_t)N_NODES * 128 * 2);
  unsigned short* projs_pk = (unsigned short*)alloc((size_t)N_NODES * 128 * 2);
  float* aggrA  = (float*)alloc((size_t)N_NODES * 64 * 4);
  float* aggrB  = (float*)alloc((size_t)N_NODES * 64 * 4);
  float* musum  = (float*)alloc(128 * 4);
  float* sqsum  = musum + 64;
  float* invc   = (float*)alloc((size_t)N_NODES * 4);
  int*   cnt    = (int*)alloc((size_t)N_NODES * 4);
  int*   lpre   = (int*)alloc((size_t)N_NODES * 4);
  int*   ptot   = (int*)alloc((size_t)SCAN_BLOCKS * 4);
  int*   wptr   = (int*)alloc((size_t)N_NODES * 4);
  int2*  ds2    = (int2*)alloc((size_t)N_EDGES * 8);
  int*   grp    = (int*)alloc((size_t)(NG + 1) * 4);
  unsigned short* eapb = (unsigned short*)alloc((size_t)N_EDGES * 64 * 2);
  unsigned short* Bp   = (unsigned short*)alloc((size_t)NL * 16 * 64 * 8 * 2);

  hipMemsetAsync(cnt, 0, N_NODES * sizeof(int), stream);
  k_init<<<LIN0_BLOCKS + CNT_BLOCKS + WPREP_BLOCKS, 256, 0, stream>>>(
      x, lin0_w, lin0_b, h0, ei, cnt, conv_wf, conv_ws, Bp);
  k_scan1<<<SCAN_BLOCKS, 256, 0, stream>>>(cnt, lpre, ptot);
  k_scan23<<<SCAN_BLOCKS, 256, 0, stream>>>(cnt, lpre, ptot, batch, wptr, invc, grp);
  // fused: CSR build + bf16 pack + MFMA nodeproj(l=0)
  k_build<<<BUILD_BLOCKS + NPM_BLOCKS, 256, 0, stream>>>(
      ei, wptr, ds2, ea, eapb, h0, conv_wf, conv_ws, projd_pk, projs_pk, aggrA);

  float* aggr_of[NL] = {aggrA, aggrB, aggrA};
  const float* hin_of[NL]  = {h0, h0, h1};
  float* hout_of[NL]       = {h0, h1, h0};

  for (int l = 0; l < NL; ++l) {
    const float* wfl = conv_wf + (size_t)l * ZD * D1;
    const float* wsl = conv_ws + (size_t)l * ZD * D1;
    if (l > 0)
      k_npm<<<NPM_BLOCKS, 256, 0, stream>>>(
          hin_of[l], hout_of[l], wfl, wsl, projd_pk, projs_pk,
          aggr_of[l - 1], aggr_of[l], invc, musum, sqsum,
          bn_gamma + (size_t)(l - 1) * D1, bn_beta + (size_t)(l - 1) * D1);
    k_edgemm<<<EDGE_GRID, 256, 0, stream>>>(
        projd_pk, projs_pk, eapb, ds2,
        Bp + (size_t)l * 16 * 64 * 8,
        conv_bf + (size_t)l * D1, conv_bs + (size_t)l * D1,
        aggr_of[l], musum, sqsum);
    k_stats<<<256, 256, 0, stream>>>(aggr_of[l], invc, musum, sqsum);
  }

  k_poolmlp<<<NG, 256, 0, stream>>>(h0, aggr_of[2], invc, musum, sqsum,
                                    bn_gamma + (size_t)2 * D1, bn_beta + (size_t)2 * D1,
                                    grp, lin1_w, lin1_b, fc_w, fc_b,
                                    lin2_w, lin2_b, (float*)d_out);
}

// Round 11
// 583.256 us; speedup vs baseline: 1.0721x; 1.0721x over previous
//
#include <hip/hip_runtime.h>
#include <hip/hip_bf16.h>

#define N_NODES 30000
#define N_EDGES 480000
#define NFEAT 92
#define EFEAT 50
#define D1 64
#define ZD 178
#define NL 3
#define NG 256
#define BN_EPS 1e-5f
#define NTILES (N_EDGES / 16)     // 30000 tiles, 1 per wave
#define EDGE_WBLK 3750            // R11: 8 waves/block, 1 tile/wave -> 3750 blocks
#define EDGE_GRID 3752            // 8 XCDs x 469, guard vbid < 3750

#define LIN0_BLOCKS 512
#define CNT_BLOCKS 1875    // E / 256
#define WPREP_BLOCKS 96    // NL*16*64*8 / 256
#define SCAN_BLOCKS ((N_NODES + 255) / 256)  // 118
#define BUILD_BLOCKS 1875  // E / 256
#define NPM_BLOCKS 1875    // MFMA nodeproj: N_NODES/16 tiles, 1 per block

typedef __attribute__((ext_vector_type(8))) short bf16x8;
typedef __attribute__((ext_vector_type(8))) unsigned short u16x8;
typedef __attribute__((ext_vector_type(4))) unsigned short u16x4;
typedef __attribute__((ext_vector_type(4))) float f32x4;

static __device__ __forceinline__ unsigned short f2bf(float v) {
  __hip_bfloat16 b = __float2bfloat16(v);
  return *(unsigned short*)&b;
}
static __device__ __forceinline__ float bfu(unsigned short u) {
  union { unsigned int i; float f; } c;
  c.i = ((unsigned int)u) << 16;
  return c.f;
}

// ---------------- R8-proven MFMA nodeproj GEMM stage ----------------
static __device__ __forceinline__ void npm_gemm(
    int i0, const float* __restrict__ wfp, const float* __restrict__ wsm,
    unsigned short* __restrict__ projd_pk, unsigned short* __restrict__ projs_pk,
    const float (*hl)[68]) {
  const int lane = threadIdx.x & 63;
  const int w = threadIdx.x >> 6;  // 0..3: combo (Wf-dst, Wf-src, Ws-dst, Ws-src)
  const float* W = (w < 2) ? wfp : wsm;
  const int roff = (w & 1) * 64;
  unsigned short* pk = (w & 1) ? projs_pk : projd_pk;
  const int slot = (w < 2) ? 0 : 4;
  const int col = lane & 15;
  const int quad = lane >> 4;

  bf16x8 Bf[4][2];
#pragma unroll
  for (int ft = 0; ft < 4; ++ft)
#pragma unroll
    for (int kh = 0; kh < 2; ++kh) {
      bf16x8 bv;
#pragma unroll
      for (int j = 0; j < 8; ++j) {
        const float v = W[(size_t)(roff + kh * 32 + quad * 8 + j) * D1 + ft * 16 + col];
        ((unsigned short*)&bv)[j] = f2bf(v);
      }
      Bf[ft][kh] = bv;
    }

  bf16x8 A0, A1;
  {
    const float4* hr0 = (const float4*)&hl[col][quad * 8];
    const float4* hr1 = (const float4*)&hl[col][32 + quad * 8];
    const float4 a0 = hr0[0], a1 = hr0[1];
    const float4 b0 = hr1[0], b1 = hr1[1];
    ((unsigned short*)&A0)[0] = f2bf(a0.x); ((unsigned short*)&A0)[1] = f2bf(a0.y);
    ((unsigned short*)&A0)[2] = f2bf(a0.z); ((unsigned short*)&A0)[3] = f2bf(a0.w);
    ((unsigned short*)&A0)[4] = f2bf(a1.x); ((unsigned short*)&A0)[5] = f2bf(a1.y);
    ((unsigned short*)&A0)[6] = f2bf(a1.z); ((unsigned short*)&A0)[7] = f2bf(a1.w);
    ((unsigned short*)&A1)[0] = f2bf(b0.x); ((unsigned short*)&A1)[1] = f2bf(b0.y);
    ((unsigned short*)&A1)[2] = f2bf(b0.z); ((unsigned short*)&A1)[3] = f2bf(b0.w);
    ((unsigned short*)&A1)[4] = f2bf(b1.x); ((unsigned short*)&A1)[5] = f2bf(b1.y);
    ((unsigned short*)&A1)[6] = f2bf(b1.z); ((unsigned short*)&A1)[7] = f2bf(b1.w);
  }

#pragma unroll
  for (int ft = 0; ft < 4; ++ft) {
    f32x4 c = {0.0f, 0.0f, 0.0f, 0.0f};
    c = __builtin_amdgcn_mfma_f32_16x16x32_bf16(A0, Bf[ft][0], c, 0, 0, 0);
    c = __builtin_amdgcn_mfma_f32_16x16x32_bf16(A1, Bf[ft][1], c, 0, 0, 0);
    const int boff = (ft * 4 + (col >> 2)) * 8 + (col & 3) + slot;
#pragma unroll
    for (int r = 0; r < 4; ++r)
      pk[(size_t)(i0 + quad * 4 + r) * 128 + boff] = f2bf(c[r]);
  }
}

// ---------------- init: lin0 + dst counts + B fragments (block-range split) --
extern "C" __global__ void __launch_bounds__(256)
k_init(const float* __restrict__ x, const float* __restrict__ w,
       const float* __restrict__ b, float* __restrict__ h,
       const int* __restrict__ ei, int* __restrict__ cnt,
       const float* __restrict__ conv_wf, const float* __restrict__ conv_ws,
       unsigned short* __restrict__ Bp) {
  const int blk = blockIdx.x;
  if (blk < LIN0_BLOCKS) {
    const int lane = threadIdx.x & 63;
    const int wave = (blk * 256 + threadIdx.x) >> 6;
    const int nw = (LIN0_BLOCKS * 256) >> 6;
    float wreg[NFEAT];
#pragma unroll
    for (int k = 0; k < NFEAT; ++k) wreg[k] = w[k * D1 + lane];
    const float bj = b[lane];
    for (int i = wave; i < N_NODES; i += nw) {
      const float2* xr = (const float2*)(x + (size_t)i * NFEAT);
      float acc = bj;
#pragma unroll
      for (int k = 0; k < NFEAT / 2; ++k) {
        const float2 v = xr[k];
        acc = fmaf(v.x, wreg[2 * k], acc);
        acc = fmaf(v.y, wreg[2 * k + 1], acc);
      }
      h[(size_t)i * D1 + lane] = fmaxf(acc, 0.0f);
    }
  } else if (blk < LIN0_BLOCKS + CNT_BLOCKS) {
    const int e = (blk - LIN0_BLOCKS) * 256 + threadIdx.x;
    if (e < N_EDGES) atomicAdd(&cnt[ei[N_EDGES + e]], 1);
  } else {
    const int idx = (blk - LIN0_BLOCKS - CNT_BLOCKS) * 256 + threadIdx.x;
    const int j = idx & 7;
    const int lane = (idx >> 3) & 63;
    const int frag = (idx >> 9) & 15;  // (m*2+t)*4+n
    const int l = idx >> 13;
    const int n = frag & 3;
    const int t = (frag >> 2) & 1;
    const int m = frag >> 3;
    const int k = t * 32 + (lane >> 4) * 8 + j;
    const int feat = (lane & 15) * 4 + n;
    float v = 0.0f;
    if (k < EFEAT) {
      const float* W = (m == 0) ? conv_wf : conv_ws;
      v = W[(size_t)l * ZD * D1 + (size_t)(128 + k) * D1 + feat];
    }
    Bp[idx] = f2bf(v);
  }
}

// ---------------- scan phase 1: per-block partial sums ----------------
extern "C" __global__ void __launch_bounds__(256)
k_scan1(const int* __restrict__ cnt, int* __restrict__ lpre, int* __restrict__ ptot) {
  const int t = threadIdx.x;
  const int idx = blockIdx.x * 256 + t;
  const int v = (idx < N_NODES) ? cnt[idx] : 0;
  __shared__ int bs[256];
  bs[t] = v;
  __syncthreads();
  for (int off = 1; off < 256; off <<= 1) {
    int u = (t >= off) ? bs[t - off] : 0;
    __syncthreads();
    bs[t] += u;
    __syncthreads();
  }
  if (idx < N_NODES) lpre[idx] = bs[t] - v;
  if (t == 255) ptot[blockIdx.x] = bs[255];
}

// scan phase 2+3: redundant block-offset scan + wptr/invc/grp
extern "C" __global__ void __launch_bounds__(256)
k_scan23(const int* __restrict__ cnt, const int* __restrict__ lpre,
         const int* __restrict__ ptot, const int* __restrict__ batch,
         int* __restrict__ wptr, float* __restrict__ invc,
         int* __restrict__ grp) {
  __shared__ int bs[128];
  const int t = threadIdx.x;
  if (t < 128) bs[t] = (t < SCAN_BLOCKS) ? ptot[t] : 0;
  __syncthreads();
  for (int off = 1; off < 128; off <<= 1) {
    int u = 0;
    if (t < 128 && t >= off) u = bs[t - off];
    __syncthreads();
    if (t < 128 && t >= off) bs[t] += u;
    __syncthreads();
  }
  const int idx = blockIdx.x * 256 + t;
  if (idx >= N_NODES) return;
  const int bid = idx >> 8;
  const int boff = (bid == 0) ? 0 : bs[bid - 1];
  wptr[idx] = boff + lpre[idx];
  invc[idx] = 1.0f / fmaxf((float)cnt[idx], 1.0f);
  const int bt = batch[idx];
  if (idx == 0)
    for (int g = 0; g <= bt; ++g) grp[g] = 0;
  else {
    const int pb = batch[idx - 1];
    for (int g = pb + 1; g <= bt; ++g) grp[g] = idx;
  }
  if (idx == N_NODES - 1)
    for (int g = bt + 1; g <= NG; ++g) grp[g] = N_NODES;
}

// ---------------- build: CSR scatter + bf16 pack + MFMA nodeproj0 -----------
extern "C" __global__ void __launch_bounds__(256)
k_build(const int* __restrict__ ei, int* __restrict__ wptr,
        int2* __restrict__ ds2, const float* __restrict__ ea,
        unsigned short* __restrict__ eapb,
        const float* __restrict__ h0, const float* __restrict__ wfl,
        const float* __restrict__ wsl, unsigned short* __restrict__ projd_pk,
        unsigned short* __restrict__ projs_pk, float* __restrict__ aggrA) {
  __shared__ __align__(16) float hl[16][68];  // union: lpos (1KB) / h tile (4.25KB)
  if (blockIdx.x >= BUILD_BLOCKS) {
    const int i0 = (blockIdx.x - BUILD_BLOCKS) * 16;
    const int tid = threadIdx.x;
    {
      const int k = tid & 63;
#pragma unroll
      for (int jj = 0; jj < 4; ++jj) {
        const int row = (tid >> 6) + jj * 4;
        const int ii = i0 + row;
        const float hv = h0[(size_t)ii * D1 + k];
        aggrA[(size_t)ii * D1 + k] = 0.0f;
        hl[row][k] = hv;
      }
    }
    __syncthreads();
    npm_gemm(i0, wfl, wsl, projd_pk, projs_pk, hl);
    return;
  }
  int* lpos = (int*)hl;
  const int e0 = blockIdx.x * 256;
  {
    const int e = e0 + threadIdx.x;
    const int d = ei[N_EDGES + e];
    const int pos = atomicAdd(&wptr[d], 1);
    ds2[pos] = make_int2(d, ei[e]);  // one 8B scatter (half the sectors)
    lpos[threadIdx.x] = pos;
  }
  __syncthreads();
  const int l16 = threadIdx.x & 15;
  const int sub = threadIdx.x >> 4;  // 0..15
#pragma unroll
  for (int r = 0; r < 16; ++r) {
    const int eb = r * 16 + sub;
    const size_t ge = e0 + eb;
    const int pos = lpos[eb];
    unsigned short o0 = 0, o1 = 0, o2 = 0, o3 = 0;
    if (l16 < 12) {
      const float4 v = *(const float4*)(ea + ge * EFEAT + l16 * 4);
      o0 = f2bf(v.x); o1 = f2bf(v.y); o2 = f2bf(v.z); o3 = f2bf(v.w);
    } else if (l16 == 12) {
      const float2 v = *(const float2*)(ea + ge * EFEAT + 48);
      o0 = f2bf(v.x); o1 = f2bf(v.y);
    }
    u16x4 st;
    st[0] = o0; st[1] = o1; st[2] = o2; st[3] = o3;
    *(u16x4*)(eapb + ((size_t)pos << 6) + l16 * 4) = st;
  }
}

// ---------------- R8: MFMA node projection (layers 1,2) ----------------
extern "C" __global__ void __launch_bounds__(256)
k_npm(const float* __restrict__ hin, float* __restrict__ hout,
      const float* __restrict__ wfp, const float* __restrict__ wsm,
      unsigned short* __restrict__ projd_pk, unsigned short* __restrict__ projs_pk,
      const float* __restrict__ aggr, float* __restrict__ aggr_z,
      const float* __restrict__ invc,
      const float* __restrict__ musum, const float* __restrict__ sqsum,
      const float* __restrict__ gamma, const float* __restrict__ beta) {
  __shared__ float hl[16][68];  // +4 pad
  const int tid = threadIdx.x;
  const int i0 = blockIdx.x * 16;

  {
    const int k = tid & 63;
    const float mu = musum[k] * (1.0f / N_NODES);
    const float var = sqsum[k] * (1.0f / N_NODES) - mu * mu;
    const float r = gamma[k] * rsqrtf(var + BN_EPS);
    const float sh = beta[k] - mu * r;
#pragma unroll
    for (int jj = 0; jj < 4; ++jj) {
      const int row = (tid >> 6) + jj * 4;
      const int ii = i0 + row;
      float hv = hin[(size_t)ii * D1 + k];
      const float av = aggr[(size_t)ii * D1 + k] * invc[ii];
      hv = fmaxf(hv + fmaf(av, r, sh), 0.0f);
      hout[(size_t)ii * D1 + k] = hv;
      aggr_z[(size_t)ii * D1 + k] = 0.0f;
      hl[row][k] = hv;
    }
  }
  __syncthreads();
  npm_gemm(i0, wfp, wsm, projd_pk, projs_pk, hl);
}

// ---------------- MFMA edge kernel: 8 waves/block, 1 tile per wave (R11) ----
// Per-wave work identical to the 585us R9 version; only block aggregation
// changes (7504 x 4-wave -> 3752 x 8-wave). Halves the CP dispatch rate
// requirement (~88 -> ~44 blocks/us) that pinned occupancy at 40%.
extern "C" __global__ void __launch_bounds__(512)
k_edgemm(const unsigned short* __restrict__ projd_pk,
         const unsigned short* __restrict__ projs_pk,
         const unsigned short* __restrict__ eapb,
         const int2* __restrict__ ds2,
         const unsigned short* __restrict__ Bp,
         const float* __restrict__ bfp, const float* __restrict__ bsp,
         float* __restrict__ aggr, float* __restrict__ musum,
         float* __restrict__ sqsum) {
  const int lane = threadIdx.x & 63;
  const int wv = threadIdx.x >> 6;  // 0..7
  const int col = lane & 15;
  const int quad = lane >> 4;
  __shared__ float mlds[8][16][68];

  const int vbid = (blockIdx.x & 7) * 469 + (blockIdx.x >> 3);
  if (blockIdx.x == 0 && wv == 0) {  // zero stats accumulators for k_stats
    musum[lane] = 0.0f;
    sqsum[lane] = 0.0f;
  }
  if (vbid >= EDGE_WBLK) return;

  const int t = vbid * 8 + wv;  // tile id; exactly NTILES waves
  const int base = t * 16;

  // independent streamed loads — all in flight together
  const int4 p01 = *(const int4*)(ds2 + base + quad * 4);      // edges r=0,1
  const int4 p23 = *(const int4*)(ds2 + base + quad * 4 + 2);  // edges r=2,3
  const int dr[4] = {p01.x, p01.z, p23.x, p23.z};
  const int sr[4] = {p01.y, p01.w, p23.y, p23.w};
  const bf16x8 Af0 = *(const bf16x8*)(eapb + ((size_t)(base + col) << 6) + quad * 8);
  const bf16x8 Af1 = *(const bf16x8*)(eapb + ((size_t)(base + col) << 6) + 32 + quad * 8);

  bf16x8 Bf[2][2][4];
#pragma unroll
  for (int m = 0; m < 2; ++m)
#pragma unroll
    for (int tt = 0; tt < 2; ++tt)
#pragma unroll
      for (int n = 0; n < 4; ++n)
        Bf[m][tt][n] = *(const bf16x8*)(Bp + ((((m * 2 + tt) * 4 + n) * 64 + lane) * 8));

  const f32x4 bf4 = *(const f32x4*)(bfp + col * 4);
  const f32x4 bs4 = *(const f32x4*)(bsp + col * 4);

  // C init from packed bf16 projections: 2 gathered 16B loads per edge row
  f32x4 aF[4], aS[4];
#pragma unroll
  for (int r = 0; r < 4; ++r) {
    const int d = dr[r];
    const int s = sr[r];
    const u16x8 pd = *(const u16x8*)(projd_pk + (size_t)d * 128 + col * 8);
    const u16x8 ss = *(const u16x8*)(projs_pk + (size_t)s * 128 + col * 8);
#pragma unroll
    for (int n = 0; n < 4; ++n) {
      aF[n][r] = bfu(pd[n]) + bfu(ss[n]) + bf4[n];
      aS[n][r] = bfu(pd[n + 4]) + bfu(ss[n + 4]) + bs4[n];
    }
  }

#pragma unroll
  for (int n = 0; n < 4; ++n) {
    aF[n] = __builtin_amdgcn_mfma_f32_16x16x32_bf16(Af0, Bf[0][0][n], aF[n], 0, 0, 0);
    aF[n] = __builtin_amdgcn_mfma_f32_16x16x32_bf16(Af1, Bf[0][1][n], aF[n], 0, 0, 0);
    aS[n] = __builtin_amdgcn_mfma_f32_16x16x32_bf16(Af0, Bf[1][0][n], aS[n], 0, 0, 0);
    aS[n] = __builtin_amdgcn_mfma_f32_16x16x32_bf16(Af1, Bf[1][1][n], aS[n], 0, 0, 0);
  }

  // epilogue: m = sigmoid(af) * softplus(as) -> LDS tile
#pragma unroll
  for (int r = 0; r < 4; ++r) {
    f32x4 mv;
#pragma unroll
    for (int n = 0; n < 4; ++n) {
      const float af = aF[n][r];
      const float as = aS[n][r];
      const float sg = __builtin_amdgcn_rcpf(1.0f + __expf(-af));
      const float sp = fmaxf(as, 0.0f) + __logf(1.0f + __expf(-fabsf(as)));
      mv[n] = sg * sp;
    }
    *(f32x4*)&mlds[wv][quad * 4 + r][col * 4] = mv;
  }
  __builtin_amdgcn_wave_barrier();

  // segmented reduce over the 16 dst-sorted CSR rows (raw sums; mean later)
  float sum = 0.0f;
  int dcur = ds2[base].x;
#pragma unroll
  for (int p = 0; p < 16; ++p) {
    sum += mlds[wv][p][lane];
    const int dnxt = (p < 15) ? ds2[base + p + 1].x : -1;
    if (dnxt != dcur) {
      atomicAdd(&aggr[(size_t)dcur * D1 + lane], sum);
      sum = 0.0f;
      dcur = dnxt;
    }
  }
}

// ---------------- BN stats over aggr*invc ----------------
extern "C" __global__ void __launch_bounds__(256)
k_stats(const float* __restrict__ aggr, const float* __restrict__ invc,
        float* __restrict__ musum, float* __restrict__ sqsum) {
  const int j = threadIdx.x & 63;
  const int rid = (blockIdx.x * blockDim.x + threadIdx.x) >> 6;
  const int rstr = (gridDim.x * blockDim.x) >> 6;
  float s = 0.0f, sq = 0.0f;
  for (int i = rid; i < N_NODES; i += rstr) {
    const float v = aggr[(size_t)i * D1 + j] * invc[i];
    s += v;
    sq = fmaf(v, v, sq);
  }
  __shared__ float ls[256], lq[256];
  ls[threadIdx.x] = s;
  lq[threadIdx.x] = sq;
  __syncthreads();
  if (threadIdx.x < 64) {
    s = ls[j] + ls[64 + j] + ls[128 + j] + ls[192 + j];
    sq = lq[j] + lq[64 + j] + lq[128 + j] + lq[192 + j];
    atomicAdd(&musum[j], s);
    atomicAdd(&sqsum[j], sq);
  }
}

// ---------------- fused pool (final BN update) + MLP chain ------------------
extern "C" __global__ void __launch_bounds__(256)
k_poolmlp(const float* __restrict__ h, const float* __restrict__ aggr,
          const float* __restrict__ invc,
          const float* __restrict__ musum, const float* __restrict__ sqsum,
          const float* __restrict__ gamma, const float* __restrict__ beta,
          const int* __restrict__ grp,
          const float* __restrict__ lin1_w, const float* __restrict__ lin1_b,
          const float* __restrict__ fc_w, const float* __restrict__ fc_b,
          const float* __restrict__ lin2_w, const float* __restrict__ lin2_b,
          float* __restrict__ out) {
  const int g = blockIdx.x;
  const int lane = threadIdx.x & 63;
  const int wv = threadIdx.x >> 6;
  const float mu = musum[lane] * (1.0f / N_NODES);
  const float var = sqsum[lane] * (1.0f / N_NODES) - mu * mu;
  const float r = gamma[lane] * rsqrtf(var + BN_EPS);
  const float sh = beta[lane] - mu * r;
  const int s = grp[g], e = grp[g + 1];
  float acc = 0.0f;
  for (int i = s + wv; i < e; i += 4) {
    const float hv = h[(size_t)i * D1 + lane];
    const float av = aggr[(size_t)i * D1 + lane] * invc[i];
    acc += fmaxf(hv + fmaf(av, r, sh), 0.0f);
  }
  __shared__ float red[4][64];
  __shared__ float vin[64];
  red[wv][lane] = acc;
  __syncthreads();
  const int j = threadIdx.x;
  float v = 0.0f;
  if (j < 64) {
    const float inv = 1.0f / fmaxf((float)(e - s), 1.0f);
    v = (red[0][j] + red[1][j] + red[2][j] + red[3][j]) * inv;
  }
  for (int layer = 0; layer < 3; ++layer) {
    if (j < 64) vin[j] = v;
    __syncthreads();
    if (j < 64) {
      const float* W;
      const float* B;
      if (layer == 0) {
        W = lin1_w;
        B = lin1_b;
      } else {
        W = fc_w + (size_t)(layer - 1) * D1 * D1;
        B = fc_b + (size_t)(layer - 1) * D1;
      }
      float a2 = B[j];
#pragma unroll 16
      for (int k = 0; k < D1; ++k) a2 = fmaf(vin[k], W[k * D1 + j], a2);
      v = fmaxf(a2, 0.0f);
    }
    __syncthreads();
  }
  if (j < 64) {
    float p = v * lin2_w[j];
#pragma unroll
    for (int off = 32; off > 0; off >>= 1) p += __shfl_down(p, off);
    if (j == 0) out[g] = p + lin2_b[0];
  }
}

extern "C" void kernel_launch(void* const* d_in, const int* in_sizes, int n_in,
                              void* d_out, int out_size, void* d_ws, size_t ws_size,
                              hipStream_t stream) {
  const float* x        = (const float*)d_in[0];
  const float* ea       = (const float*)d_in[1];
  const float* lin0_w   = (const float*)d_in[2];
  const float* lin0_b   = (const float*)d_in[3];
  const float* conv_wf  = (const float*)d_in[4];
  const float* conv_bf  = (const float*)d_in[5];
  const float* conv_ws  = (const float*)d_in[6];
  const float* conv_bs  = (const float*)d_in[7];
  const float* bn_gamma = (const float*)d_in[8];
  const float* bn_beta  = (const float*)d_in[9];
  const float* lin1_w   = (const float*)d_in[10];
  const float* lin1_b   = (const float*)d_in[11];
  const float* fc_w     = (const float*)d_in[12];
  const float* fc_b     = (const float*)d_in[13];
  const float* lin2_w   = (const float*)d_in[14];
  const float* lin2_b   = (const float*)d_in[15];
  const int*   ei       = (const int*)d_in[16];
  const int*   batch    = (const int*)d_in[17];

  uintptr_t p = (uintptr_t)d_ws;
  auto alloc = [&](size_t bytes) {
    p = (p + 255) & ~(size_t)255;
    void* r = (void*)p;
    p += bytes;
    return r;
  };
  float* h0     = (float*)alloc((size_t)N_NODES * 64 * 4);
  float* h1     = (float*)alloc((size_t)N_NODES * 64 * 4);
  unsigned short* projd_pk = (unsigned short*)alloc((size_t)N_NODES * 128 * 2);
  unsigned short* projs_pk = (unsigned short*)alloc((size_t)N_NODES * 128 * 2);
  float* aggrA  = (float*)alloc((size_t)N_NODES * 64 * 4);
  float* aggrB  = (float*)alloc((size_t)N_NODES * 64 * 4);
  float* musum  = (float*)alloc(128 * 4);
  float* sqsum  = musum + 64;
  float* invc   = (float*)alloc((size_t)N_NODES * 4);
  int*   cnt    = (int*)alloc((size_t)N_NODES * 4);
  int*   lpre   = (int*)alloc((size_t)N_NODES * 4);
  int*   ptot   = (int*)alloc((size_t)SCAN_BLOCKS * 4);
  int*   wptr   = (int*)alloc((size_t)N_NODES * 4);
  int2*  ds2    = (int2*)alloc((size_t)N_EDGES * 8);
  int*   grp    = (int*)alloc((size_t)(NG + 1) * 4);
  unsigned short* eapb = (unsigned short*)alloc((size_t)N_EDGES * 64 * 2);
  unsigned short* Bp   = (unsigned short*)alloc((size_t)NL * 16 * 64 * 8 * 2);

  hipMemsetAsync(cnt, 0, N_NODES * sizeof(int), stream);
  k_init<<<LIN0_BLOCKS + CNT_BLOCKS + WPREP_BLOCKS, 256, 0, stream>>>(
      x, lin0_w, lin0_b, h0, ei, cnt, conv_wf, conv_ws, Bp);
  k_scan1<<<SCAN_BLOCKS, 256, 0, stream>>>(cnt, lpre, ptot);
  k_scan23<<<SCAN_BLOCKS, 256, 0, stream>>>(cnt, lpre, ptot, batch, wptr, invc, grp);
  // fused: CSR build + bf16 pack + MFMA nodeproj(l=0)
  k_build<<<BUILD_BLOCKS + NPM_BLOCKS, 256, 0, stream>>>(
      ei, wptr, ds2, ea, eapb, h0, conv_wf, conv_ws, projd_pk, projs_pk, aggrA);

  float* aggr_of[NL] = {aggrA, aggrB, aggrA};
  const float* hin_of[NL]  = {h0, h0, h1};
  float* hout_of[NL]       = {h0, h1, h0};

  for (int l = 0; l < NL; ++l) {
    const float* wfl = conv_wf + (size_t)l * ZD * D1;
    const float* wsl = conv_ws + (size_t)l * ZD * D1;
    if (l > 0)
      k_npm<<<NPM_BLOCKS, 256, 0, stream>>>(
          hin_of[l], hout_of[l], wfl, wsl, projd_pk, projs_pk,
          aggr_of[l - 1], aggr_of[l], invc, musum, sqsum,
          bn_gamma + (size_t)(l - 1) * D1, bn_beta + (size_t)(l - 1) * D1);
    k_edgemm<<<EDGE_GRID, 512, 0, stream>>>(
        projd_pk, projs_pk, eapb, ds2,
        Bp + (size_t)l * 16 * 64 * 8,
        conv_bf + (size_t)l * D1, conv_bs + (size_t)l * D1,
        aggr_of[l], musum, sqsum);
    k_stats<<<256, 256, 0, stream>>>(aggr_of[l], invc, musum, sqsum);
  }

  k_poolmlp<<<NG, 256, 0, stream>>>(h0, aggr_of[2], invc, musum, sqsum,
                                    bn_gamma + (size_t)2 * D1, bn_beta + (size_t)2 * D1,
                                    grp, lin1_w, lin1_b, fc_w, fc_b,
                                    lin2_w, lin2_b, (float*)d_out);
}

// Round 12
// 527.811 us; speedup vs baseline: 1.1847x; 1.1050x over previous
//
#include <hip/hip_runtime.h>
#include <hip/hip_bf16.h>

#define N_NODES 30000
#define N_EDGES 480000
#define NFEAT 92
#define EFEAT 50
#define D1 64
#define ZD 178
#define NL 3
#define NG 256
#define BN_EPS 1e-5f
#define NTILES (N_EDGES / 16)     // 30000 tiles, 1 per wave
#define EDGE_WBLK 3750            // 8 waves/block, 1 tile/wave -> 3750 blocks
#define EDGE_GRID 3752            // 8 XCDs x 469, guard vbid < 3750

#define LIN0_BLOCKS 512
#define CNT_BLOCKS 1875    // E / 256
#define WPREP_BLOCKS 96    // NL*16*64*8 / 256
#define SCAN_BLOCKS ((N_NODES + 255) / 256)  // 118
#define BUILD_BLOCKS 1875  // E / 256
#define NPM_BLOCKS 1875    // MFMA nodeproj: N_NODES/16 tiles, 1 per block

typedef __attribute__((ext_vector_type(8))) short bf16x8;
typedef __attribute__((ext_vector_type(8))) unsigned short u16x8;
typedef __attribute__((ext_vector_type(4))) unsigned short u16x4;
typedef __attribute__((ext_vector_type(4))) float f32x4;

static __device__ __forceinline__ unsigned short f2bf(float v) {
  __hip_bfloat16 b = __float2bfloat16(v);
  return *(unsigned short*)&b;
}
static __device__ __forceinline__ float bfu(unsigned short u) {
  union { unsigned int i; float f; } c;
  c.i = ((unsigned int)u) << 16;
  return c.f;
}

// ---------------- R8-proven MFMA nodeproj GEMM stage ----------------
static __device__ __forceinline__ void npm_gemm(
    int i0, const float* __restrict__ wfp, const float* __restrict__ wsm,
    unsigned short* __restrict__ projd_pk, unsigned short* __restrict__ projs_pk,
    const float (*hl)[68]) {
  const int lane = threadIdx.x & 63;
  const int w = threadIdx.x >> 6;  // 0..3: combo (Wf-dst, Wf-src, Ws-dst, Ws-src)
  const float* W = (w < 2) ? wfp : wsm;
  const int roff = (w & 1) * 64;
  unsigned short* pk = (w & 1) ? projs_pk : projd_pk;
  const int slot = (w < 2) ? 0 : 4;
  const int col = lane & 15;
  const int quad = lane >> 4;

  bf16x8 Bf[4][2];
#pragma unroll
  for (int ft = 0; ft < 4; ++ft)
#pragma unroll
    for (int kh = 0; kh < 2; ++kh) {
      bf16x8 bv;
#pragma unroll
      for (int j = 0; j < 8; ++j) {
        const float v = W[(size_t)(roff + kh * 32 + quad * 8 + j) * D1 + ft * 16 + col];
        ((unsigned short*)&bv)[j] = f2bf(v);
      }
      Bf[ft][kh] = bv;
    }

  bf16x8 A0, A1;
  {
    const float4* hr0 = (const float4*)&hl[col][quad * 8];
    const float4* hr1 = (const float4*)&hl[col][32 + quad * 8];
    const float4 a0 = hr0[0], a1 = hr0[1];
    const float4 b0 = hr1[0], b1 = hr1[1];
    ((unsigned short*)&A0)[0] = f2bf(a0.x); ((unsigned short*)&A0)[1] = f2bf(a0.y);
    ((unsigned short*)&A0)[2] = f2bf(a0.z); ((unsigned short*)&A0)[3] = f2bf(a0.w);
    ((unsigned short*)&A0)[4] = f2bf(a1.x); ((unsigned short*)&A0)[5] = f2bf(a1.y);
    ((unsigned short*)&A0)[6] = f2bf(a1.z); ((unsigned short*)&A0)[7] = f2bf(a1.w);
    ((unsigned short*)&A1)[0] = f2bf(b0.x); ((unsigned short*)&A1)[1] = f2bf(b0.y);
    ((unsigned short*)&A1)[2] = f2bf(b0.z); ((unsigned short*)&A1)[3] = f2bf(b0.w);
    ((unsigned short*)&A1)[4] = f2bf(b1.x); ((unsigned short*)&A1)[5] = f2bf(b1.y);
    ((unsigned short*)&A1)[6] = f2bf(b1.z); ((unsigned short*)&A1)[7] = f2bf(b1.w);
  }

#pragma unroll
  for (int ft = 0; ft < 4; ++ft) {
    f32x4 c = {0.0f, 0.0f, 0.0f, 0.0f};
    c = __builtin_amdgcn_mfma_f32_16x16x32_bf16(A0, Bf[ft][0], c, 0, 0, 0);
    c = __builtin_amdgcn_mfma_f32_16x16x32_bf16(A1, Bf[ft][1], c, 0, 0, 0);
    const int boff = (ft * 4 + (col >> 2)) * 8 + (col & 3) + slot;
#pragma unroll
    for (int r = 0; r < 4; ++r)
      pk[(size_t)(i0 + quad * 4 + r) * 128 + boff] = f2bf(c[r]);
  }
}

// ---------------- init: lin0 + dst counts + B fragments (block-range split) --
extern "C" __global__ void __launch_bounds__(256)
k_init(const float* __restrict__ x, const float* __restrict__ w,
       const float* __restrict__ b, float* __restrict__ h,
       const int* __restrict__ ei, int* __restrict__ cnt,
       const float* __restrict__ conv_wf, const float* __restrict__ conv_ws,
       unsigned short* __restrict__ Bp) {
  const int blk = blockIdx.x;
  if (blk < LIN0_BLOCKS) {
    const int lane = threadIdx.x & 63;
    const int wave = (blk * 256 + threadIdx.x) >> 6;
    const int nw = (LIN0_BLOCKS * 256) >> 6;
    float wreg[NFEAT];
#pragma unroll
    for (int k = 0; k < NFEAT; ++k) wreg[k] = w[k * D1 + lane];
    const float bj = b[lane];
    for (int i = wave; i < N_NODES; i += nw) {
      const float2* xr = (const float2*)(x + (size_t)i * NFEAT);
      float acc = bj;
#pragma unroll
      for (int k = 0; k < NFEAT / 2; ++k) {
        const float2 v = xr[k];
        acc = fmaf(v.x, wreg[2 * k], acc);
        acc = fmaf(v.y, wreg[2 * k + 1], acc);
      }
      h[(size_t)i * D1 + lane] = fmaxf(acc, 0.0f);
    }
  } else if (blk < LIN0_BLOCKS + CNT_BLOCKS) {
    const int e = (blk - LIN0_BLOCKS) * 256 + threadIdx.x;
    if (e < N_EDGES) atomicAdd(&cnt[ei[N_EDGES + e]], 1);
  } else {
    const int idx = (blk - LIN0_BLOCKS - CNT_BLOCKS) * 256 + threadIdx.x;
    const int j = idx & 7;
    const int lane = (idx >> 3) & 63;
    const int frag = (idx >> 9) & 15;  // (m*2+t)*4+n
    const int l = idx >> 13;
    const int n = frag & 3;
    const int t = (frag >> 2) & 1;
    const int m = frag >> 3;
    const int k = t * 32 + (lane >> 4) * 8 + j;
    const int feat = (lane & 15) * 4 + n;
    float v = 0.0f;
    if (k < EFEAT) {
      const float* W = (m == 0) ? conv_wf : conv_ws;
      v = W[(size_t)l * ZD * D1 + (size_t)(128 + k) * D1 + feat];
    }
    Bp[idx] = f2bf(v);
  }
}

// ---------------- scan phase 1: per-block partial sums ----------------
extern "C" __global__ void __launch_bounds__(256)
k_scan1(const int* __restrict__ cnt, int* __restrict__ lpre, int* __restrict__ ptot) {
  const int t = threadIdx.x;
  const int idx = blockIdx.x * 256 + t;
  const int v = (idx < N_NODES) ? cnt[idx] : 0;
  __shared__ int bs[256];
  bs[t] = v;
  __syncthreads();
  for (int off = 1; off < 256; off <<= 1) {
    int u = (t >= off) ? bs[t - off] : 0;
    __syncthreads();
    bs[t] += u;
    __syncthreads();
  }
  if (idx < N_NODES) lpre[idx] = bs[t] - v;
  if (t == 255) ptot[blockIdx.x] = bs[255];
}

// scan phase 2+3: redundant block-offset scan + wptr/invc/grp
extern "C" __global__ void __launch_bounds__(256)
k_scan23(const int* __restrict__ cnt, const int* __restrict__ lpre,
         const int* __restrict__ ptot, const int* __restrict__ batch,
         int* __restrict__ wptr, float* __restrict__ invc,
         int* __restrict__ grp) {
  __shared__ int bs[128];
  const int t = threadIdx.x;
  if (t < 128) bs[t] = (t < SCAN_BLOCKS) ? ptot[t] : 0;
  __syncthreads();
  for (int off = 1; off < 128; off <<= 1) {
    int u = 0;
    if (t < 128 && t >= off) u = bs[t - off];
    __syncthreads();
    if (t < 128 && t >= off) bs[t] += u;
    __syncthreads();
  }
  const int idx = blockIdx.x * 256 + t;
  if (idx >= N_NODES) return;
  const int bid = idx >> 8;
  const int boff = (bid == 0) ? 0 : bs[bid - 1];
  wptr[idx] = boff + lpre[idx];
  invc[idx] = 1.0f / fmaxf((float)cnt[idx], 1.0f);
  const int bt = batch[idx];
  if (idx == 0)
    for (int g = 0; g <= bt; ++g) grp[g] = 0;
  else {
    const int pb = batch[idx - 1];
    for (int g = pb + 1; g <= bt; ++g) grp[g] = idx;
  }
  if (idx == N_NODES - 1)
    for (int g = bt + 1; g <= NG; ++g) grp[g] = N_NODES;
}

// ---------------- build: CSR scatter + bf16 pack + MFMA nodeproj0 -----------
extern "C" __global__ void __launch_bounds__(256)
k_build(const int* __restrict__ ei, int* __restrict__ wptr,
        int2* __restrict__ ds2, const float* __restrict__ ea,
        unsigned short* __restrict__ eapb,
        const float* __restrict__ h0, const float* __restrict__ wfl,
        const float* __restrict__ wsl, unsigned short* __restrict__ projd_pk,
        unsigned short* __restrict__ projs_pk, float* __restrict__ aggrA) {
  __shared__ __align__(16) float hl[16][68];  // union: lpos (1KB) / h tile (4.25KB)
  if (blockIdx.x >= BUILD_BLOCKS) {
    const int i0 = (blockIdx.x - BUILD_BLOCKS) * 16;
    const int tid = threadIdx.x;
    {
      const int k = tid & 63;
#pragma unroll
      for (int jj = 0; jj < 4; ++jj) {
        const int row = (tid >> 6) + jj * 4;
        const int ii = i0 + row;
        const float hv = h0[(size_t)ii * D1 + k];
        aggrA[(size_t)ii * D1 + k] = 0.0f;
        hl[row][k] = hv;
      }
    }
    __syncthreads();
    npm_gemm(i0, wfl, wsl, projd_pk, projs_pk, hl);
    return;
  }
  int* lpos = (int*)hl;
  const int e0 = blockIdx.x * 256;
  {
    const int e = e0 + threadIdx.x;
    const int d = ei[N_EDGES + e];
    const int pos = atomicAdd(&wptr[d], 1);
    ds2[pos] = make_int2(d, ei[e]);  // one 8B scatter (half the sectors)
    lpos[threadIdx.x] = pos;
  }
  __syncthreads();
  const int l16 = threadIdx.x & 15;
  const int sub = threadIdx.x >> 4;  // 0..15
#pragma unroll
  for (int r = 0; r < 16; ++r) {
    const int eb = r * 16 + sub;
    const size_t ge = e0 + eb;
    const int pos = lpos[eb];
    unsigned short o0 = 0, o1 = 0, o2 = 0, o3 = 0;
    if (l16 < 12) {
      const float4 v = *(const float4*)(ea + ge * EFEAT + l16 * 4);
      o0 = f2bf(v.x); o1 = f2bf(v.y); o2 = f2bf(v.z); o3 = f2bf(v.w);
    } else if (l16 == 12) {
      const float2 v = *(const float2*)(ea + ge * EFEAT + 48);
      o0 = f2bf(v.x); o1 = f2bf(v.y);
    }
    u16x4 st;
    st[0] = o0; st[1] = o1; st[2] = o2; st[3] = o3;
    *(u16x4*)(eapb + ((size_t)pos << 6) + l16 * 4) = st;
  }
}

// ---------------- R8: MFMA node projection (layers 1,2) ----------------
extern "C" __global__ void __launch_bounds__(256)
k_npm(const float* __restrict__ hin, float* __restrict__ hout,
      const float* __restrict__ wfp, const float* __restrict__ wsm,
      unsigned short* __restrict__ projd_pk, unsigned short* __restrict__ projs_pk,
      const float* __restrict__ aggr, float* __restrict__ aggr_z,
      const float* __restrict__ invc,
      const float* __restrict__ musum, const float* __restrict__ sqsum,
      const float* __restrict__ gamma, const float* __restrict__ beta) {
  __shared__ float hl[16][68];  // +4 pad
  const int tid = threadIdx.x;
  const int i0 = blockIdx.x * 16;

  {
    const int k = tid & 63;
    const float mu = musum[k] * (1.0f / N_NODES);
    const float var = sqsum[k] * (1.0f / N_NODES) - mu * mu;
    const float r = gamma[k] * rsqrtf(var + BN_EPS);
    const float sh = beta[k] - mu * r;
#pragma unroll
    for (int jj = 0; jj < 4; ++jj) {
      const int row = (tid >> 6) + jj * 4;
      const int ii = i0 + row;
      float hv = hin[(size_t)ii * D1 + k];
      const float av = aggr[(size_t)ii * D1 + k] * invc[ii];
      hv = fmaxf(hv + fmaf(av, r, sh), 0.0f);
      hout[(size_t)ii * D1 + k] = hv;
      aggr_z[(size_t)ii * D1 + k] = 0.0f;
      hl[row][k] = hv;
    }
  }
  __syncthreads();
  npm_gemm(i0, wfp, wsm, projd_pk, projs_pk, hl);
}

// ---------------- MFMA edge kernel: 8 waves/block, 1 tile/wave --------------
// R12: Bf weights staged block-wide into LDS once (16KB), waves read frags via
// ds_read_b128 instead of 16 global loads/wave. Cuts per-tile L1 line work
// (16KB of L1 line traffic per wave -> one-time per block, amortized 8 tiles).
extern "C" __global__ void __launch_bounds__(512)
k_edgemm(const unsigned short* __restrict__ projd_pk,
         const unsigned short* __restrict__ projs_pk,
         const unsigned short* __restrict__ eapb,
         const int2* __restrict__ ds2,
         const unsigned short* __restrict__ Bp,
         const float* __restrict__ bfp, const float* __restrict__ bsp,
         float* __restrict__ aggr, float* __restrict__ musum,
         float* __restrict__ sqsum) {
  const int lane = threadIdx.x & 63;
  const int wv = threadIdx.x >> 6;  // 0..7
  const int col = lane & 15;
  const int quad = lane >> 4;
  __shared__ float mlds[8][16][68];
  __shared__ __align__(16) unsigned short Bsh[16 * 64 * 8];  // 16KB

  const int vbid = (blockIdx.x & 7) * 469 + (blockIdx.x >> 3);
  if (blockIdx.x == 0 && wv == 0) {  // zero stats accumulators for k_stats
    musum[lane] = 0.0f;
    sqsum[lane] = 0.0f;
  }
  if (vbid >= EDGE_WBLK) return;  // block-uniform: whole block exits pre-sync

  // stage Bp -> LDS (512 thr x 16 shorts, coalesced)
  {
    const int tid = threadIdx.x;
    *(u16x8*)(Bsh + tid * 16) = *(const u16x8*)(Bp + tid * 16);
    *(u16x8*)(Bsh + tid * 16 + 8) = *(const u16x8*)(Bp + tid * 16 + 8);
  }
  __syncthreads();

  const int t = vbid * 8 + wv;  // tile id; exactly NTILES waves
  const int base = t * 16;

  // independent streamed loads — all in flight together
  const int4 p01 = *(const int4*)(ds2 + base + quad * 4);      // edges r=0,1
  const int4 p23 = *(const int4*)(ds2 + base + quad * 4 + 2);  // edges r=2,3
  const int dr[4] = {p01.x, p01.z, p23.x, p23.z};
  const int sr[4] = {p01.y, p01.w, p23.y, p23.w};
  const bf16x8 Af0 = *(const bf16x8*)(eapb + ((size_t)(base + col) << 6) + quad * 8);
  const bf16x8 Af1 = *(const bf16x8*)(eapb + ((size_t)(base + col) << 6) + 32 + quad * 8);

  bf16x8 Bf[2][2][4];
#pragma unroll
  for (int m = 0; m < 2; ++m)
#pragma unroll
    for (int tt = 0; tt < 2; ++tt)
#pragma unroll
      for (int n = 0; n < 4; ++n)
        Bf[m][tt][n] = *(const bf16x8*)(Bsh + ((((m * 2 + tt) * 4 + n) * 64 + lane) * 8));

  const f32x4 bf4 = *(const f32x4*)(bfp + col * 4);
  const f32x4 bs4 = *(const f32x4*)(bsp + col * 4);

  // C init from packed bf16 projections: 2 gathered 16B loads per edge row
  f32x4 aF[4], aS[4];
#pragma unroll
  for (int r = 0; r < 4; ++r) {
    const int d = dr[r];
    const int s = sr[r];
    const u16x8 pd = *(const u16x8*)(projd_pk + (size_t)d * 128 + col * 8);
    const u16x8 ss = *(const u16x8*)(projs_pk + (size_t)s * 128 + col * 8);
#pragma unroll
    for (int n = 0; n < 4; ++n) {
      aF[n][r] = bfu(pd[n]) + bfu(ss[n]) + bf4[n];
      aS[n][r] = bfu(pd[n + 4]) + bfu(ss[n + 4]) + bs4[n];
    }
  }

#pragma unroll
  for (int n = 0; n < 4; ++n) {
    aF[n] = __builtin_amdgcn_mfma_f32_16x16x32_bf16(Af0, Bf[0][0][n], aF[n], 0, 0, 0);
    aF[n] = __builtin_amdgcn_mfma_f32_16x16x32_bf16(Af1, Bf[0][1][n], aF[n], 0, 0, 0);
    aS[n] = __builtin_amdgcn_mfma_f32_16x16x32_bf16(Af0, Bf[1][0][n], aS[n], 0, 0, 0);
    aS[n] = __builtin_amdgcn_mfma_f32_16x16x32_bf16(Af1, Bf[1][1][n], aS[n], 0, 0, 0);
  }

  // epilogue: m = sigmoid(af) * softplus(as) -> LDS tile
#pragma unroll
  for (int r = 0; r < 4; ++r) {
    f32x4 mv;
#pragma unroll
    for (int n = 0; n < 4; ++n) {
      const float af = aF[n][r];
      const float as = aS[n][r];
      const float sg = __builtin_amdgcn_rcpf(1.0f + __expf(-af));
      const float sp = fmaxf(as, 0.0f) + __logf(1.0f + __expf(-fabsf(as)));
      mv[n] = sg * sp;
    }
    *(f32x4*)&mlds[wv][quad * 4 + r][col * 4] = mv;
  }
  __builtin_amdgcn_wave_barrier();

  // segmented reduce over the 16 dst-sorted CSR rows (raw sums; mean later)
  float sum = 0.0f;
  int dcur = ds2[base].x;
#pragma unroll
  for (int p = 0; p < 16; ++p) {
    sum += mlds[wv][p][lane];
    const int dnxt = (p < 15) ? ds2[base + p + 1].x : -1;
    if (dnxt != dcur) {
      atomicAdd(&aggr[(size_t)dcur * D1 + lane], sum);
      sum = 0.0f;
      dcur = dnxt;
    }
  }
}

// ---------------- BN stats over aggr*invc ----------------
extern "C" __global__ void __launch_bounds__(256)
k_stats(const float* __restrict__ aggr, const float* __restrict__ invc,
        float* __restrict__ musum, float* __restrict__ sqsum) {
  const int j = threadIdx.x & 63;
  const int rid = (blockIdx.x * blockDim.x + threadIdx.x) >> 6;
  const int rstr = (gridDim.x * blockDim.x) >> 6;
  float s = 0.0f, sq = 0.0f;
  for (int i = rid; i < N_NODES; i += rstr) {
    const float v = aggr[(size_t)i * D1 + j] * invc[i];
    s += v;
    sq = fmaf(v, v, sq);
  }
  __shared__ float ls[256], lq[256];
  ls[threadIdx.x] = s;
  lq[threadIdx.x] = sq;
  __syncthreads();
  if (threadIdx.x < 64) {
    s = ls[j] + ls[64 + j] + ls[128 + j] + ls[192 + j];
    sq = lq[j] + lq[64 + j] + lq[128 + j] + lq[192 + j];
    atomicAdd(&musum[j], s);
    atomicAdd(&sqsum[j], sq);
  }
}

// ---------------- fused pool (final BN update) + MLP chain ------------------
extern "C" __global__ void __launch_bounds__(256)
k_poolmlp(const float* __restrict__ h, const float* __restrict__ aggr,
          const float* __restrict__ invc,
          const float* __restrict__ musum, const float* __restrict__ sqsum,
          const float* __restrict__ gamma, const float* __restrict__ beta,
          const int* __restrict__ grp,
          const float* __restrict__ lin1_w, const float* __restrict__ lin1_b,
          const float* __restrict__ fc_w, const float* __restrict__ fc_b,
          const float* __restrict__ lin2_w, const float* __restrict__ lin2_b,
          float* __restrict__ out) {
  const int g = blockIdx.x;
  const int lane = threadIdx.x & 63;
  const int wv = threadIdx.x >> 6;
  const float mu = musum[lane] * (1.0f / N_NODES);
  const float var = sqsum[lane] * (1.0f / N_NODES) - mu * mu;
  const float r = gamma[lane] * rsqrtf(var + BN_EPS);
  const float sh = beta[lane] - mu * r;
  const int s = grp[g], e = grp[g + 1];
  float acc = 0.0f;
  for (int i = s + wv; i < e; i += 4) {
    const float hv = h[(size_t)i * D1 + lane];
    const float av = aggr[(size_t)i * D1 + lane] * invc[i];
    acc += fmaxf(hv + fmaf(av, r, sh), 0.0f);
  }
  __shared__ float red[4][64];
  __shared__ float vin[64];
  red[wv][lane] = acc;
  __syncthreads();
  const int j = threadIdx.x;
  float v = 0.0f;
  if (j < 64) {
    const float inv = 1.0f / fmaxf((float)(e - s), 1.0f);
    v = (red[0][j] + red[1][j] + red[2][j] + red[3][j]) * inv;
  }
  for (int layer = 0; layer < 3; ++layer) {
    if (j < 64) vin[j] = v;
    __syncthreads();
    if (j < 64) {
      const float* W;
      const float* B;
      if (layer == 0) {
        W = lin1_w;
        B = lin1_b;
      } else {
        W = fc_w + (size_t)(layer - 1) * D1 * D1;
        B = fc_b + (size_t)(layer - 1) * D1;
      }
      float a2 = B[j];
#pragma unroll 16
      for (int k = 0; k < D1; ++k) a2 = fmaf(vin[k], W[k * D1 + j], a2);
      v = fmaxf(a2, 0.0f);
    }
    __syncthreads();
  }
  if (j < 64) {
    float p = v * lin2_w[j];
#pragma unroll
    for (int off = 32; off > 0; off >>= 1) p += __shfl_down(p, off);
    if (j == 0) out[g] = p + lin2_b[0];
  }
}

extern "C" void kernel_launch(void* const* d_in, const int* in_sizes, int n_in,
                              void* d_out, int out_size, void* d_ws, size_t ws_size,
                              hipStream_t stream) {
  const float* x        = (const float*)d_in[0];
  const float* ea       = (const float*)d_in[1];
  const float* lin0_w   = (const float*)d_in[2];
  const float* lin0_b   = (const float*)d_in[3];
  const float* conv_wf  = (const float*)d_in[4];
  const float* conv_bf  = (const float*)d_in[5];
  const float* conv_ws  = (const float*)d_in[6];
  const float* conv_bs  = (const float*)d_in[7];
  const float* bn_gamma = (const float*)d_in[8];
  const float* bn_beta  = (const float*)d_in[9];
  const float* lin1_w   = (const float*)d_in[10];
  const float* lin1_b   = (const float*)d_in[11];
  const float* fc_w     = (const float*)d_in[12];
  const float* fc_b     = (const float*)d_in[13];
  const float* lin2_w   = (const float*)d_in[14];
  const float* lin2_b   = (const float*)d_in[15];
  const int*   ei       = (const int*)d_in[16];
  const int*   batch    = (const int*)d_in[17];

  uintptr_t p = (uintptr_t)d_ws;
  auto alloc = [&](size_t bytes) {
    p = (p + 255) & ~(size_t)255;
    void* r = (void*)p;
    p += bytes;
    return r;
  };
  float* h0     = (float*)alloc((size_t)N_NODES * 64 * 4);
  float* h1     = (float*)alloc((size_t)N_NODES * 64 * 4);
  unsigned short* projd_pk = (unsigned short*)alloc((size_t)N_NODES * 128 * 2);
  unsigned short* projs_pk = (unsigned short*)alloc((size_t)N_NODES * 128 * 2);
  float* aggrA  = (float*)alloc((size_t)N_NODES * 64 * 4);
  float* aggrB  = (float*)alloc((size_t)N_NODES * 64 * 4);
  float* musum  = (float*)alloc(128 * 4);
  float* sqsum  = musum + 64;
  float* invc   = (float*)alloc((size_t)N_NODES * 4);
  int*   cnt    = (int*)alloc((size_t)N_NODES * 4);
  int*   lpre   = (int*)alloc((size_t)N_NODES * 4);
  int*   ptot   = (int*)alloc((size_t)SCAN_BLOCKS * 4);
  int*   wptr   = (int*)alloc((size_t)N_NODES * 4);
  int2*  ds2    = (int2*)alloc((size_t)N_EDGES * 8);
  int*   grp    = (int*)alloc((size_t)(NG + 1) * 4);
  unsigned short* eapb = (unsigned short*)alloc((size_t)N_EDGES * 64 * 2);
  unsigned short* Bp   = (unsigned short*)alloc((size_t)NL * 16 * 64 * 8 * 2);

  hipMemsetAsync(cnt, 0, N_NODES * sizeof(int), stream);
  k_init<<<LIN0_BLOCKS + CNT_BLOCKS + WPREP_BLOCKS, 256, 0, stream>>>(
      x, lin0_w, lin0_b, h0, ei, cnt, conv_wf, conv_ws, Bp);
  k_scan1<<<SCAN_BLOCKS, 256, 0, stream>>>(cnt, lpre, ptot);
  k_scan23<<<SCAN_BLOCKS, 256, 0, stream>>>(cnt, lpre, ptot, batch, wptr, invc, grp);
  // fused: CSR build + bf16 pack + MFMA nodeproj(l=0)
  k_build<<<BUILD_BLOCKS + NPM_BLOCKS, 256, 0, stream>>>(
      ei, wptr, ds2, ea, eapb, h0, conv_wf, conv_ws, projd_pk, projs_pk, aggrA);

  float* aggr_of[NL] = {aggrA, aggrB, aggrA};
  const float* hin_of[NL]  = {h0, h0, h1};
  float* hout_of[NL]       = {h0, h1, h0};

  for (int l = 0; l < NL; ++l) {
    const float* wfl = conv_wf + (size_t)l * ZD * D1;
    const float* wsl = conv_ws + (size_t)l * ZD * D1;
    if (l > 0)
      k_npm<<<NPM_BLOCKS, 256, 0, stream>>>(
          hin_of[l], hout_of[l], wfl, wsl, projd_pk, projs_pk,
          aggr_of[l - 1], aggr_of[l], invc, musum, sqsum,
          bn_gamma + (size_t)(l - 1) * D1, bn_beta + (size_t)(l - 1) * D1);
    k_edgemm<<<EDGE_GRID, 512, 0, stream>>>(
        projd_pk, projs_pk, eapb, ds2,
        Bp + (size_t)l * 16 * 64 * 8,
        conv_bf + (size_t)l * D1, conv_bs + (size_t)l * D1,
        aggr_of[l], musum, sqsum);
    k_stats<<<256, 256, 0, stream>>>(aggr_of[l], invc, musum, sqsum);
  }

  k_poolmlp<<<NG, 256, 0, stream>>>(h0, aggr_of[2], invc, musum, sqsum,
                                    bn_gamma + (size_t)2 * D1, bn_beta + (size_t)2 * D1,
                                    grp, lin1_w, lin1_b, fc_w, fc_b,
                                    lin2_w, lin2_b, (float*)d_out);
}

// Round 13
// 506.747 us; speedup vs baseline: 1.2340x; 1.0416x over previous
//
#include <hip/hip_runtime.h>
#include <hip/hip_bf16.h>

#define N_NODES 30000
#define N_EDGES 480000
#define NFEAT 92
#define EFEAT 50
#define D1 64
#define ZD 178
#define NL 3
#define NG 256
#define BN_EPS 1e-5f
#define NTILES (N_EDGES / 16)     // 30000 tiles, 1 per wave
#define EDGE_WBLK 3750            // 8 waves/block, 1 tile/wave -> 3750 blocks
#define EDGE_GRID 3752            // 8 XCDs x 469, guard vbid < 3750

#define LIN0M_BLOCKS 1875  // R13: MFMA lin0, 16-node tiles
#define CNT_BLOCKS 1875    // E / 256
#define WPREP_BLOCKS 96    // NL*16*64*8 / 256
#define SCAN_BLOCKS ((N_NODES + 255) / 256)  // 118
#define BUILD_BLOCKS 1875  // E / 256
#define NPM_BLOCKS 1875    // MFMA nodeproj: N_NODES/16 tiles, 1 per block

typedef __attribute__((ext_vector_type(8))) short bf16x8;
typedef __attribute__((ext_vector_type(8))) unsigned short u16x8;
typedef __attribute__((ext_vector_type(4))) unsigned short u16x4;
typedef __attribute__((ext_vector_type(4))) float f32x4;

static __device__ __forceinline__ unsigned short f2bf(float v) {
  __hip_bfloat16 b = __float2bfloat16(v);
  return *(unsigned short*)&b;
}
static __device__ __forceinline__ float bfu(unsigned short u) {
  union { unsigned int i; float f; } c;
  c.i = ((unsigned int)u) << 16;
  return c.f;
}

// ---------------- R8-proven MFMA nodeproj GEMM stage ----------------
static __device__ __forceinline__ void npm_gemm(
    int i0, const float* __restrict__ wfp, const float* __restrict__ wsm,
    unsigned short* __restrict__ projd_pk, unsigned short* __restrict__ projs_pk,
    const float (*hl)[68]) {
  const int lane = threadIdx.x & 63;
  const int w = threadIdx.x >> 6;  // 0..3: combo (Wf-dst, Wf-src, Ws-dst, Ws-src)
  const float* W = (w < 2) ? wfp : wsm;
  const int roff = (w & 1) * 64;
  unsigned short* pk = (w & 1) ? projs_pk : projd_pk;
  const int slot = (w < 2) ? 0 : 4;
  const int col = lane & 15;
  const int quad = lane >> 4;

  bf16x8 Bf[4][2];
#pragma unroll
  for (int ft = 0; ft < 4; ++ft)
#pragma unroll
    for (int kh = 0; kh < 2; ++kh) {
      bf16x8 bv;
#pragma unroll
      for (int j = 0; j < 8; ++j) {
        const float v = W[(size_t)(roff + kh * 32 + quad * 8 + j) * D1 + ft * 16 + col];
        ((unsigned short*)&bv)[j] = f2bf(v);
      }
      Bf[ft][kh] = bv;
    }

  bf16x8 A0, A1;
  {
    const float4* hr0 = (const float4*)&hl[col][quad * 8];
    const float4* hr1 = (const float4*)&hl[col][32 + quad * 8];
    const float4 a0 = hr0[0], a1 = hr0[1];
    const float4 b0 = hr1[0], b1 = hr1[1];
    ((unsigned short*)&A0)[0] = f2bf(a0.x); ((unsigned short*)&A0)[1] = f2bf(a0.y);
    ((unsigned short*)&A0)[2] = f2bf(a0.z); ((unsigned short*)&A0)[3] = f2bf(a0.w);
    ((unsigned short*)&A0)[4] = f2bf(a1.x); ((unsigned short*)&A0)[5] = f2bf(a1.y);
    ((unsigned short*)&A0)[6] = f2bf(a1.z); ((unsigned short*)&A0)[7] = f2bf(a1.w);
    ((unsigned short*)&A1)[0] = f2bf(b0.x); ((unsigned short*)&A1)[1] = f2bf(b0.y);
    ((unsigned short*)&A1)[2] = f2bf(b0.z); ((unsigned short*)&A1)[3] = f2bf(b0.w);
    ((unsigned short*)&A1)[4] = f2bf(b1.x); ((unsigned short*)&A1)[5] = f2bf(b1.y);
    ((unsigned short*)&A1)[6] = f2bf(b1.z); ((unsigned short*)&A1)[7] = f2bf(b1.w);
  }

#pragma unroll
  for (int ft = 0; ft < 4; ++ft) {
    f32x4 c = {0.0f, 0.0f, 0.0f, 0.0f};
    c = __builtin_amdgcn_mfma_f32_16x16x32_bf16(A0, Bf[ft][0], c, 0, 0, 0);
    c = __builtin_amdgcn_mfma_f32_16x16x32_bf16(A1, Bf[ft][1], c, 0, 0, 0);
    const int boff = (ft * 4 + (col >> 2)) * 8 + (col & 3) + slot;
#pragma unroll
    for (int r = 0; r < 4; ++r)
      pk[(size_t)(i0 + quad * 4 + r) * 128 + boff] = f2bf(c[r]);
  }
}

// ---------------- init: MFMA lin0 + dst counts + B fragments ----------------
// R13: lin0 [30000x92]x[92x64] moved to matrix pipe (3rd application of the
// R8 recipe). 16-node tiles; K padded 92->96 with zeros; bias+relu epilogue.
extern "C" __global__ void __launch_bounds__(256)
k_init(const float* __restrict__ x, const float* __restrict__ wmat,
       const float* __restrict__ b, float* __restrict__ h,
       const int* __restrict__ ei, int* __restrict__ cnt,
       const float* __restrict__ conv_wf, const float* __restrict__ conv_ws,
       unsigned short* __restrict__ Bp) {
  const int blk = blockIdx.x;
  if (blk < LIN0M_BLOCKS) {
    __shared__ __align__(16) float xl[16][100];  // 96 used + pad
    const int i0 = blk * 16;
    const int tid = threadIdx.x;
    for (int idx = tid; idx < 16 * NFEAT; idx += 256)
      xl[idx / NFEAT][idx % NFEAT] = x[(size_t)i0 * NFEAT + idx];
    if (tid < 128) xl[tid >> 3][NFEAT + (tid & 7)] = 0.0f;  // zero pad 92..99
    __syncthreads();

    const int lane = tid & 63;
    const int fw = tid >> 6;  // f-tile 0..3
    const int col = lane & 15;
    const int quad = lane >> 4;

    bf16x8 Bf[3];
#pragma unroll
    for (int kh = 0; kh < 3; ++kh) {
      bf16x8 bv;
#pragma unroll
      for (int j = 0; j < 8; ++j) {
        const int k = kh * 32 + quad * 8 + j;
        const float v = (k < NFEAT) ? wmat[(size_t)k * D1 + fw * 16 + col] : 0.0f;
        ((unsigned short*)&bv)[j] = f2bf(v);
      }
      Bf[kh] = bv;
    }
    bf16x8 Af[3];
#pragma unroll
    for (int kh = 0; kh < 3; ++kh) {
      const float4* hr = (const float4*)&xl[col][kh * 32 + quad * 8];
      const float4 a0 = hr[0], a1 = hr[1];
      bf16x8 av;
      ((unsigned short*)&av)[0] = f2bf(a0.x); ((unsigned short*)&av)[1] = f2bf(a0.y);
      ((unsigned short*)&av)[2] = f2bf(a0.z); ((unsigned short*)&av)[3] = f2bf(a0.w);
      ((unsigned short*)&av)[4] = f2bf(a1.x); ((unsigned short*)&av)[5] = f2bf(a1.y);
      ((unsigned short*)&av)[6] = f2bf(a1.z); ((unsigned short*)&av)[7] = f2bf(a1.w);
      Af[kh] = av;
    }
    f32x4 c = {0.0f, 0.0f, 0.0f, 0.0f};
    c = __builtin_amdgcn_mfma_f32_16x16x32_bf16(Af[0], Bf[0], c, 0, 0, 0);
    c = __builtin_amdgcn_mfma_f32_16x16x32_bf16(Af[1], Bf[1], c, 0, 0, 0);
    c = __builtin_amdgcn_mfma_f32_16x16x32_bf16(Af[2], Bf[2], c, 0, 0, 0);
    const float bj = b[fw * 16 + col];
#pragma unroll
    for (int r = 0; r < 4; ++r)
      h[(size_t)(i0 + quad * 4 + r) * D1 + fw * 16 + col] = fmaxf(c[r] + bj, 0.0f);
  } else if (blk < LIN0M_BLOCKS + CNT_BLOCKS) {
    const int e = (blk - LIN0M_BLOCKS) * 256 + threadIdx.x;
    if (e < N_EDGES) atomicAdd(&cnt[ei[N_EDGES + e]], 1);
  } else {
    const int idx = (blk - LIN0M_BLOCKS - CNT_BLOCKS) * 256 + threadIdx.x;
    const int j = idx & 7;
    const int lane = (idx >> 3) & 63;
    const int frag = (idx >> 9) & 15;  // (m*2+t)*4+n
    const int l = idx >> 13;
    const int n = frag & 3;
    const int t = (frag >> 2) & 1;
    const int m = frag >> 3;
    const int k = t * 32 + (lane >> 4) * 8 + j;
    const int feat = (lane & 15) * 4 + n;
    float v = 0.0f;
    if (k < EFEAT) {
      const float* W = (m == 0) ? conv_wf : conv_ws;
      v = W[(size_t)l * ZD * D1 + (size_t)(128 + k) * D1 + feat];
    }
    Bp[idx] = f2bf(v);
  }
}

// ---------------- scan phase 1: per-block partial sums ----------------
extern "C" __global__ void __launch_bounds__(256)
k_scan1(const int* __restrict__ cnt, int* __restrict__ lpre, int* __restrict__ ptot) {
  const int t = threadIdx.x;
  const int idx = blockIdx.x * 256 + t;
  const int v = (idx < N_NODES) ? cnt[idx] : 0;
  __shared__ int bs[256];
  bs[t] = v;
  __syncthreads();
  for (int off = 1; off < 256; off <<= 1) {
    int u = (t >= off) ? bs[t - off] : 0;
    __syncthreads();
    bs[t] += u;
    __syncthreads();
  }
  if (idx < N_NODES) lpre[idx] = bs[t] - v;
  if (t == 255) ptot[blockIdx.x] = bs[255];
}

// scan phase 2+3: redundant block-offset scan + wptr/invc/grp
extern "C" __global__ void __launch_bounds__(256)
k_scan23(const int* __restrict__ cnt, const int* __restrict__ lpre,
         const int* __restrict__ ptot, const int* __restrict__ batch,
         int* __restrict__ wptr, float* __restrict__ invc,
         int* __restrict__ grp) {
  __shared__ int bs[128];
  const int t = threadIdx.x;
  if (t < 128) bs[t] = (t < SCAN_BLOCKS) ? ptot[t] : 0;
  __syncthreads();
  for (int off = 1; off < 128; off <<= 1) {
    int u = 0;
    if (t < 128 && t >= off) u = bs[t - off];
    __syncthreads();
    if (t < 128 && t >= off) bs[t] += u;
    __syncthreads();
  }
  const int idx = blockIdx.x * 256 + t;
  if (idx >= N_NODES) return;
  const int bid = idx >> 8;
  const int boff = (bid == 0) ? 0 : bs[bid - 1];
  wptr[idx] = boff + lpre[idx];
  invc[idx] = 1.0f / fmaxf((float)cnt[idx], 1.0f);
  const int bt = batch[idx];
  if (idx == 0)
    for (int g = 0; g <= bt; ++g) grp[g] = 0;
  else {
    const int pb = batch[idx - 1];
    for (int g = pb + 1; g <= bt; ++g) grp[g] = idx;
  }
  if (idx == N_NODES - 1)
    for (int g = bt + 1; g <= NG; ++g) grp[g] = N_NODES;
}

// ---------------- build: CSR scatter + bf16 pack + MFMA nodeproj0 -----------
extern "C" __global__ void __launch_bounds__(256)
k_build(const int* __restrict__ ei, int* __restrict__ wptr,
        int2* __restrict__ ds2, const float* __restrict__ ea,
        unsigned short* __restrict__ eapb,
        const float* __restrict__ h0, const float* __restrict__ wfl,
        const float* __restrict__ wsl, unsigned short* __restrict__ projd_pk,
        unsigned short* __restrict__ projs_pk, float* __restrict__ aggrA) {
  __shared__ __align__(16) float hl[16][68];  // union: lpos (1KB) / h tile (4.25KB)
  if (blockIdx.x >= BUILD_BLOCKS) {
    const int i0 = (blockIdx.x - BUILD_BLOCKS) * 16;
    const int tid = threadIdx.x;
    {
      const int k = tid & 63;
#pragma unroll
      for (int jj = 0; jj < 4; ++jj) {
        const int row = (tid >> 6) + jj * 4;
        const int ii = i0 + row;
        const float hv = h0[(size_t)ii * D1 + k];
        aggrA[(size_t)ii * D1 + k] = 0.0f;
        hl[row][k] = hv;
      }
    }
    __syncthreads();
    npm_gemm(i0, wfl, wsl, projd_pk, projs_pk, hl);
    return;
  }
  int* lpos = (int*)hl;
  const int e0 = blockIdx.x * 256;
  {
    const int e = e0 + threadIdx.x;
    const int d = ei[N_EDGES + e];
    const int pos = atomicAdd(&wptr[d], 1);
    ds2[pos] = make_int2(d, ei[e]);  // one 8B scatter (half the sectors)
    lpos[threadIdx.x] = pos;
  }
  __syncthreads();
  const int l16 = threadIdx.x & 15;
  const int sub = threadIdx.x >> 4;  // 0..15
#pragma unroll
  for (int r = 0; r < 16; ++r) {
    const int eb = r * 16 + sub;
    const size_t ge = e0 + eb;
    const int pos = lpos[eb];
    unsigned short o0 = 0, o1 = 0, o2 = 0, o3 = 0;
    if (l16 < 12) {
      const float4 v = *(const float4*)(ea + ge * EFEAT + l16 * 4);
      o0 = f2bf(v.x); o1 = f2bf(v.y); o2 = f2bf(v.z); o3 = f2bf(v.w);
    } else if (l16 == 12) {
      const float2 v = *(const float2*)(ea + ge * EFEAT + 48);
      o0 = f2bf(v.x); o1 = f2bf(v.y);
    }
    u16x4 st;
    st[0] = o0; st[1] = o1; st[2] = o2; st[3] = o3;
    *(u16x4*)(eapb + ((size_t)pos << 6) + l16 * 4) = st;
  }
}

// ---------------- R8: MFMA node projection (layers 1,2) ----------------
extern "C" __global__ void __launch_bounds__(256)
k_npm(const float* __restrict__ hin, float* __restrict__ hout,
      const float* __restrict__ wfp, const float* __restrict__ wsm,
      unsigned short* __restrict__ projd_pk, unsigned short* __restrict__ projs_pk,
      const float* __restrict__ aggr, float* __restrict__ aggr_z,
      const float* __restrict__ invc,
      const float* __restrict__ musum, const float* __restrict__ sqsum,
      const float* __restrict__ gamma, const float* __restrict__ beta) {
  __shared__ float hl[16][68];  // +4 pad
  const int tid = threadIdx.x;
  const int i0 = blockIdx.x * 16;

  {
    const int k = tid & 63;
    const float mu = musum[k] * (1.0f / N_NODES);
    const float var = sqsum[k] * (1.0f / N_NODES) - mu * mu;
    const float r = gamma[k] * rsqrtf(var + BN_EPS);
    const float sh = beta[k] - mu * r;
#pragma unroll
    for (int jj = 0; jj < 4; ++jj) {
      const int row = (tid >> 6) + jj * 4;
      const int ii = i0 + row;
      float hv = hin[(size_t)ii * D1 + k];
      const float av = aggr[(size_t)ii * D1 + k] * invc[ii];
      hv = fmaxf(hv + fmaf(av, r, sh), 0.0f);
      hout[(size_t)ii * D1 + k] = hv;
      aggr_z[(size_t)ii * D1 + k] = 0.0f;
      hl[row][k] = hv;
    }
  }
  __syncthreads();
  npm_gemm(i0, wfp, wsm, projd_pk, projs_pk, hl);
}

// ---------------- MFMA edge kernel: 8 waves/block, 1 tile/wave --------------
// R12: Bf weights staged block-wide into LDS once (16KB).
extern "C" __global__ void __launch_bounds__(512)
k_edgemm(const unsigned short* __restrict__ projd_pk,
         const unsigned short* __restrict__ projs_pk,
         const unsigned short* __restrict__ eapb,
         const int2* __restrict__ ds2,
         const unsigned short* __restrict__ Bp,
         const float* __restrict__ bfp, const float* __restrict__ bsp,
         float* __restrict__ aggr, float* __restrict__ musum,
         float* __restrict__ sqsum) {
  const int lane = threadIdx.x & 63;
  const int wv = threadIdx.x >> 6;  // 0..7
  const int col = lane & 15;
  const int quad = lane >> 4;
  __shared__ float mlds[8][16][68];
  __shared__ __align__(16) unsigned short Bsh[16 * 64 * 8];  // 16KB

  const int vbid = (blockIdx.x & 7) * 469 + (blockIdx.x >> 3);
  if (blockIdx.x == 0 && wv == 0) {  // zero stats accumulators for k_stats
    musum[lane] = 0.0f;
    sqsum[lane] = 0.0f;
  }
  if (vbid >= EDGE_WBLK) return;  // block-uniform: whole block exits pre-sync

  // stage Bp -> LDS (512 thr x 16 shorts, coalesced)
  {
    const int tid = threadIdx.x;
    *(u16x8*)(Bsh + tid * 16) = *(const u16x8*)(Bp + tid * 16);
    *(u16x8*)(Bsh + tid * 16 + 8) = *(const u16x8*)(Bp + tid * 16 + 8);
  }
  __syncthreads();

  const int t = vbid * 8 + wv;  // tile id; exactly NTILES waves
  const int base = t * 16;

  // independent streamed loads — all in flight together
  const int4 p01 = *(const int4*)(ds2 + base + quad * 4);      // edges r=0,1
  const int4 p23 = *(const int4*)(ds2 + base + quad * 4 + 2);  // edges r=2,3
  const int dr[4] = {p01.x, p01.z, p23.x, p23.z};
  const int sr[4] = {p01.y, p01.w, p23.y, p23.w};
  const bf16x8 Af0 = *(const bf16x8*)(eapb + ((size_t)(base + col) << 6) + quad * 8);
  const bf16x8 Af1 = *(const bf16x8*)(eapb + ((size_t)(base + col) << 6) + 32 + quad * 8);

  bf16x8 Bf[2][2][4];
#pragma unroll
  for (int m = 0; m < 2; ++m)
#pragma unroll
    for (int tt = 0; tt < 2; ++tt)
#pragma unroll
      for (int n = 0; n < 4; ++n)
        Bf[m][tt][n] = *(const bf16x8*)(Bsh + ((((m * 2 + tt) * 4 + n) * 64 + lane) * 8));

  const f32x4 bf4 = *(const f32x4*)(bfp + col * 4);
  const f32x4 bs4 = *(const f32x4*)(bsp + col * 4);

  // C init from packed bf16 projections: 2 gathered 16B loads per edge row
  f32x4 aF[4], aS[4];
#pragma unroll
  for (int r = 0; r < 4; ++r) {
    const int d = dr[r];
    const int s = sr[r];
    const u16x8 pd = *(const u16x8*)(projd_pk + (size_t)d * 128 + col * 8);
    const u16x8 ss = *(const u16x8*)(projs_pk + (size_t)s * 128 + col * 8);
#pragma unroll
    for (int n = 0; n < 4; ++n) {
      aF[n][r] = bfu(pd[n]) + bfu(ss[n]) + bf4[n];
      aS[n][r] = bfu(pd[n + 4]) + bfu(ss[n + 4]) + bs4[n];
    }
  }

#pragma unroll
  for (int n = 0; n < 4; ++n) {
    aF[n] = __builtin_amdgcn_mfma_f32_16x16x32_bf16(Af0, Bf[0][0][n], aF[n], 0, 0, 0);
    aF[n] = __builtin_amdgcn_mfma_f32_16x16x32_bf16(Af1, Bf[0][1][n], aF[n], 0, 0, 0);
    aS[n] = __builtin_amdgcn_mfma_f32_16x16x32_bf16(Af0, Bf[1][0][n], aS[n], 0, 0, 0);
    aS[n] = __builtin_amdgcn_mfma_f32_16x16x32_bf16(Af1, Bf[1][1][n], aS[n], 0, 0, 0);
  }

  // epilogue: m = sigmoid(af) * softplus(as) -> LDS tile
#pragma unroll
  for (int r = 0; r < 4; ++r) {
    f32x4 mv;
#pragma unroll
    for (int n = 0; n < 4; ++n) {
      const float af = aF[n][r];
      const float as = aS[n][r];
      const float sg = __builtin_amdgcn_rcpf(1.0f + __expf(-af));
      const float sp = fmaxf(as, 0.0f) + __logf(1.0f + __expf(-fabsf(as)));
      mv[n] = sg * sp;
    }
    *(f32x4*)&mlds[wv][quad * 4 + r][col * 4] = mv;
  }
  __builtin_amdgcn_wave_barrier();

  // segmented reduce over the 16 dst-sorted CSR rows (raw sums; mean later)
  float sum = 0.0f;
  int dcur = ds2[base].x;
#pragma unroll
  for (int p = 0; p < 16; ++p) {
    sum += mlds[wv][p][lane];
    const int dnxt = (p < 15) ? ds2[base + p + 1].x : -1;
    if (dnxt != dcur) {
      atomicAdd(&aggr[(size_t)dcur * D1 + lane], sum);
      sum = 0.0f;
      dcur = dnxt;
    }
  }
}

// ---------------- BN stats over aggr*invc ----------------
extern "C" __global__ void __launch_bounds__(256)
k_stats(const float* __restrict__ aggr, const float* __restrict__ invc,
        float* __restrict__ musum, float* __restrict__ sqsum) {
  const int j = threadIdx.x & 63;
  const int rid = (blockIdx.x * blockDim.x + threadIdx.x) >> 6;
  const int rstr = (gridDim.x * blockDim.x) >> 6;
  float s = 0.0f, sq = 0.0f;
  for (int i = rid; i < N_NODES; i += rstr) {
    const float v = aggr[(size_t)i * D1 + j] * invc[i];
    s += v;
    sq = fmaf(v, v, sq);
  }
  __shared__ float ls[256], lq[256];
  ls[threadIdx.x] = s;
  lq[threadIdx.x] = sq;
  __syncthreads();
  if (threadIdx.x < 64) {
    s = ls[j] + ls[64 + j] + ls[128 + j] + ls[192 + j];
    sq = lq[j] + lq[64 + j] + lq[128 + j] + lq[192 + j];
    atomicAdd(&musum[j], s);
    atomicAdd(&sqsum[j], sq);
  }
}

// ---------------- fused pool (final BN update) + MLP chain ------------------
extern "C" __global__ void __launch_bounds__(256)
k_poolmlp(const float* __restrict__ h, const float* __restrict__ aggr,
          const float* __restrict__ invc,
          const float* __restrict__ musum, const float* __restrict__ sqsum,
          const float* __restrict__ gamma, const float* __restrict__ beta,
          const int* __restrict__ grp,
          const float* __restrict__ lin1_w, const float* __restrict__ lin1_b,
          const float* __restrict__ fc_w, const float* __restrict__ fc_b,
          const float* __restrict__ lin2_w, const float* __restrict__ lin2_b,
          float* __restrict__ out) {
  const int g = blockIdx.x;
  const int lane = threadIdx.x & 63;
  const int wv = threadIdx.x >> 6;
  const float mu = musum[lane] * (1.0f / N_NODES);
  const float var = sqsum[lane] * (1.0f / N_NODES) - mu * mu;
  const float r = gamma[lane] * rsqrtf(var + BN_EPS);
  const float sh = beta[lane] - mu * r;
  const int s = grp[g], e = grp[g + 1];
  float acc = 0.0f;
  for (int i = s + wv; i < e; i += 4) {
    const float hv = h[(size_t)i * D1 + lane];
    const float av = aggr[(size_t)i * D1 + lane] * invc[i];
    acc += fmaxf(hv + fmaf(av, r, sh), 0.0f);
  }
  __shared__ float red[4][64];
  __shared__ float vin[64];
  red[wv][lane] = acc;
  __syncthreads();
  const int j = threadIdx.x;
  float v = 0.0f;
  if (j < 64) {
    const float inv = 1.0f / fmaxf((float)(e - s), 1.0f);
    v = (red[0][j] + red[1][j] + red[2][j] + red[3][j]) * inv;
  }
  for (int layer = 0; layer < 3; ++layer) {
    if (j < 64) vin[j] = v;
    __syncthreads();
    if (j < 64) {
      const float* W;
      const float* B;
      if (layer == 0) {
        W = lin1_w;
        B = lin1_b;
      } else {
        W = fc_w + (size_t)(layer - 1) * D1 * D1;
        B = fc_b + (size_t)(layer - 1) * D1;
      }
      float a2 = B[j];
#pragma unroll 16
      for (int k = 0; k < D1; ++k) a2 = fmaf(vin[k], W[k * D1 + j], a2);
      v = fmaxf(a2, 0.0f);
    }
    __syncthreads();
  }
  if (j < 64) {
    float p = v * lin2_w[j];
#pragma unroll
    for (int off = 32; off > 0; off >>= 1) p += __shfl_down(p, off);
    if (j == 0) out[g] = p + lin2_b[0];
  }
}

extern "C" void kernel_launch(void* const* d_in, const int* in_sizes, int n_in,
                              void* d_out, int out_size, void* d_ws, size_t ws_size,
                              hipStream_t stream) {
  const float* x        = (const float*)d_in[0];
  const float* ea       = (const float*)d_in[1];
  const float* lin0_w   = (const float*)d_in[2];
  const float* lin0_b   = (const float*)d_in[3];
  const float* conv_wf  = (const float*)d_in[4];
  const float* conv_bf  = (const float*)d_in[5];
  const float* conv_ws  = (const float*)d_in[6];
  const float* conv_bs  = (const float*)d_in[7];
  const float* bn_gamma = (const float*)d_in[8];
  const float* bn_beta  = (const float*)d_in[9];
  const float* lin1_w   = (const float*)d_in[10];
  const float* lin1_b   = (const float*)d_in[11];
  const float* fc_w     = (const float*)d_in[12];
  const float* fc_b     = (const float*)d_in[13];
  const float* lin2_w   = (const float*)d_in[14];
  const float* lin2_b   = (const float*)d_in[15];
  const int*   ei       = (const int*)d_in[16];
  const int*   batch    = (const int*)d_in[17];

  uintptr_t p = (uintptr_t)d_ws;
  auto alloc = [&](size_t bytes) {
    p = (p + 255) & ~(size_t)255;
    void* r = (void*)p;
    p += bytes;
    return r;
  };
  float* h0     = (float*)alloc((size_t)N_NODES * 64 * 4);
  float* h1     = (float*)alloc((size_t)N_NODES * 64 * 4);
  unsigned short* projd_pk = (unsigned short*)alloc((size_t)N_NODES * 128 * 2);
  unsigned short* projs_pk = (unsigned short*)alloc((size_t)N_NODES * 128 * 2);
  float* aggrA  = (float*)alloc((size_t)N_NODES * 64 * 4);
  float* aggrB  = (float*)alloc((size_t)N_NODES * 64 * 4);
  float* musum  = (float*)alloc(128 * 4);
  float* sqsum  = musum + 64;
  float* invc   = (float*)alloc((size_t)N_NODES * 4);
  int*   cnt    = (int*)alloc((size_t)N_NODES * 4);
  int*   lpre   = (int*)alloc((size_t)N_NODES * 4);
  int*   ptot   = (int*)alloc((size_t)SCAN_BLOCKS * 4);
  int*   wptr   = (int*)alloc((size_t)N_NODES * 4);
  int2*  ds2    = (int2*)alloc((size_t)N_EDGES * 8);
  int*   grp    = (int*)alloc((size_t)(NG + 1) * 4);
  unsigned short* eapb = (unsigned short*)alloc((size_t)N_EDGES * 64 * 2);
  unsigned short* Bp   = (unsigned short*)alloc((size_t)NL * 16 * 64 * 8 * 2);

  hipMemsetAsync(cnt, 0, N_NODES * sizeof(int), stream);
  k_init<<<LIN0M_BLOCKS + CNT_BLOCKS + WPREP_BLOCKS, 256, 0, stream>>>(
      x, lin0_w, lin0_b, h0, ei, cnt, conv_wf, conv_ws, Bp);
  k_scan1<<<SCAN_BLOCKS, 256, 0, stream>>>(cnt, lpre, ptot);
  k_scan23<<<SCAN_BLOCKS, 256, 0, stream>>>(cnt, lpre, ptot, batch, wptr, invc, grp);
  // fused: CSR build + bf16 pack + MFMA nodeproj(l=0)
  k_build<<<BUILD_BLOCKS + NPM_BLOCKS, 256, 0, stream>>>(
      ei, wptr, ds2, ea, eapb, h0, conv_wf, conv_ws, projd_pk, projs_pk, aggrA);

  float* aggr_of[NL] = {aggrA, aggrB, aggrA};
  const float* hin_of[NL]  = {h0, h0, h1};
  float* hout_of[NL]       = {h0, h1, h0};

  for (int l = 0; l < NL; ++l) {
    const float* wfl = conv_wf + (size_t)l * ZD * D1;
    const float* wsl = conv_ws + (size_t)l * ZD * D1;
    if (l > 0)
      k_npm<<<NPM_BLOCKS, 256, 0, stream>>>(
          hin_of[l], hout_of[l], wfl, wsl, projd_pk, projs_pk,
          aggr_of[l - 1], aggr_of[l], invc, musum, sqsum,
          bn_gamma + (size_t)(l - 1) * D1, bn_beta + (size_t)(l - 1) * D1);
    k_edgemm<<<EDGE_GRID, 512, 0, stream>>>(
        projd_pk, projs_pk, eapb, ds2,
        Bp + (size_t)l * 16 * 64 * 8,
        conv_bf + (size_t)l * D1, conv_bs + (size_t)l * D1,
        aggr_of[l], musum, sqsum);
    k_stats<<<256, 256, 0, stream>>>(aggr_of[l], invc, musum, sqsum);
  }

  k_poolmlp<<<NG, 256, 0, stream>>>(h0, aggr_of[2], invc, musum, sqsum,
                                    bn_gamma + (size_t)2 * D1, bn_beta + (size_t)2 * D1,
                                    grp, lin1_w, lin1_b, fc_w, fc_b,
                                    lin2_w, lin2_b, (float*)d_out);
}